// Round 13
// baseline (194.296 us; speedup 1.0000x reference)
//
#include <hip/hip_runtime.h>
#include <math.h>

#define NSLOT 256
#define HWN   16384
#define D_    256
#define BB    4
#define NSEL  768
#define NPOS  512
#define NHEAD 8

// global->LDS DMA: size B per lane; LDS dest is wave-uniform base (HW adds lane*size);
// GLOBAL SOURCE IS PER-LANE (R12 lesson: uniform source -> 64 copies of 16B).
#define GLD16(g, l)                                                        \
  __builtin_amdgcn_global_load_lds(                                        \
      (__attribute__((address_space(1))) void*)(g),                        \
      (__attribute__((address_space(3))) void*)(l), 16, 0, 0)
#define GLD4(g, l)                                                         \
  __builtin_amdgcn_global_load_lds(                                        \
      (__attribute__((address_space(1))) void*)(g),                        \
      (__attribute__((address_space(3))) void*)(l), 4, 0, 0)

#define BFLO(u) __uint_as_float((u) << 16)
#define BFHI(u) __uint_as_float((u) & 0xffff0000u)

__device__ __forceinline__ unsigned short f2bf(float x) {   // RNE bf16
  unsigned u = __float_as_uint(x);
  unsigned r = u + 0x7fffu + ((u >> 16) & 1u);
  return (unsigned short)(r >> 16);
}
__device__ __forceinline__ unsigned int pk2(float a, float b) {
  return (unsigned)f2bf(a) | ((unsigned)f2bf(b) << 16);
}

// Reduce 8 per-lane values over all 64 lanes simultaneously.
__device__ __forceinline__ float reduce8x64(const float p[8], int lane) {
  float v[4];
#pragma unroll
  for (int h = 0; h < 4; h++) {
    float keep = (lane & 32) ? p[h + 4] : p[h];
    float send = (lane & 32) ? p[h] : p[h + 4];
    v[h] = keep + __shfl_xor(send, 32, 64);
  }
  float w[2];
#pragma unroll
  for (int h = 0; h < 2; h++) {
    float keep = (lane & 16) ? v[h + 2] : v[h];
    float send = (lane & 16) ? v[h] : v[h + 2];
    w[h] = keep + __shfl_xor(send, 16, 64);
  }
  float r;
  {
    float keep = (lane & 8) ? w[1] : w[0];
    float send = (lane & 8) ? w[0] : w[1];
    r = keep + __shfl_xor(send, 8, 64);
  }
  r += __shfl_xor(r, 4, 64);
  r += __shfl_xor(r, 2, 64);
  r += __shfl_xor(r, 1, 64);
  return r;
}

// ---------------- Kernel P: pack kpf[row][0:256]=bf16(f+p), [256:512]=bf16(f) ----------------
__global__ __launch_bounds__(256) void pack_kernel(const float* __restrict__ f,
                                                   const float* __restrict__ p,
                                                   unsigned short* __restrict__ kpf) {
  int stride = gridDim.x * 256;
  for (int u = blockIdx.x * 256 + threadIdx.x; u < HWN * BB * 32; u += stride) {
    int row = u >> 5, c8 = (u & 31) << 3;
    const float4* f4 = (const float4*)(f + (size_t)row * D_ + c8);
    const float4* p4 = (const float4*)(p + (size_t)row * D_ + c8);
    float4 a0 = f4[0], a1 = f4[1], b0 = p4[0], b1 = p4[1];
    uint4 kp, ff;
    kp.x = pk2(a0.x + b0.x, a0.y + b0.y);
    kp.y = pk2(a0.z + b0.z, a0.w + b0.w);
    kp.z = pk2(a1.x + b1.x, a1.y + b1.y);
    kp.w = pk2(a1.z + b1.z, a1.w + b1.w);
    ff.x = pk2(a0.x, a0.y); ff.y = pk2(a0.z, a0.w);
    ff.z = pk2(a1.x, a1.y); ff.w = pk2(a1.z, a1.w);
    *(uint4*)(kpf + (size_t)row * 512 + c8) = kp;
    *(uint4*)(kpf + (size_t)row * 512 + 256 + c8) = ff;
  }
}

// ---------------- Kernel A: per-slot top-768 stable select (1024 thr) ----------------
__global__ __launch_bounds__(1024) void topk_kernel(const float* __restrict__ curio,
                                                    int* __restrict__ feat_sel) {
  __shared__ unsigned int hist[4096];
  __shared__ unsigned int wsum[16];
  __shared__ unsigned long long skey[2048];
  __shared__ int sBstar;
  __shared__ unsigned int sCount;
  int s = blockIdx.x;
  int t = threadIdx.x;
  int wave = t >> 6, lane = t & 63;
  const float* row = curio + (size_t)s * HWN;

  for (int i = t; i < 4096; i += 1024) hist[i] = 0;
  if (t == 0) sCount = 0;
  __syncthreads();
  for (int j = t; j < HWN; j += 1024) {
    unsigned int bits = __float_as_uint(row[j]);   // values in [0,1): bits monotone
    atomicAdd(&hist[bits >> 18], 1u);
  }
  __syncthreads();
  unsigned int cs = hist[t * 4] + hist[t * 4 + 1] + hist[t * 4 + 2] + hist[t * 4 + 3];
  unsigned int v = cs;
#pragma unroll
  for (int off = 1; off < 64; off <<= 1) {
    unsigned int u = __shfl_down(v, off, 64);
    if (lane + off < 64) v += u;       // suffix over lanes >= lane (this wave)
  }
  if (lane == 0) wsum[wave] = v;
  __syncthreads();
  unsigned int above = 0;
  for (int w2 = wave + 1; w2 < 16; w2++) above += wsum[w2];
  unsigned int sufAfter = above + (v - cs);
  if (sufAfter < NSEL && sufAfter + cs >= NSEL) {
    unsigned int local = sufAfter;
    for (int b = t * 4 + 3; b >= t * 4; b--) {
      unsigned int c = hist[b];
      if (local + c >= NSEL) { sBstar = b; break; }
      local += c;
    }
  }
  __syncthreads();
  int bstar = sBstar;
  for (int j = t; j < HWN; j += 1024) {
    unsigned int bits = __float_as_uint(row[j]);
    if ((int)(bits >> 18) >= bstar) {
      unsigned int pos = atomicAdd(&sCount, 1u);
      if (pos < 2048)
        skey[pos] = ((unsigned long long)bits << 14) | (unsigned long long)(16383 - j);
    }
  }
  __syncthreads();
  unsigned int M = sCount;
  int SZ = (M <= 1024) ? 1024 : 2048;
  for (int i = t; i < SZ; i += 1024) if (i >= (int)M) skey[i] = 0ull;
  for (int k = 2; k <= SZ; k <<= 1) {
    for (int j2 = k >> 1; j2 > 0; j2 >>= 1) {
      __syncthreads();
      for (int i = t; i < SZ; i += 1024) {
        int l = i ^ j2;
        if (l > i) {
          unsigned long long a = skey[i], b = skey[l];
          bool dir = ((i & k) == 0);
          if ((a < b) == dir) { skey[i] = b; skey[l] = a; }
        }
      }
    }
  }
  __syncthreads();
  for (int r = t; r < NSEL; r += 1024)
    feat_sel[s * NSEL + r] = 16383 - (int)(skey[r] & 16383ull);
}

// ---------------- Kernel B: q projection + qk = Wk^T q + qksum (per slot, 256 thr) ----------------
__global__ __launch_bounds__(256) void qproj_kernel(const float* __restrict__ slots,
                                                    const float* __restrict__ ipw,
                                                    const float* __restrict__ ipb,
                                                    float* __restrict__ qk_g,
                                                    float* __restrict__ qbk_g,
                                                    float* __restrict__ qksum_g) {
  __shared__ float srow[D_];
  __shared__ float qrow[D_];
  int s = blockIdx.x, t = threadIdx.x;
  srow[t] = slots[s * D_ + t];
  __syncthreads();
  {
    const float* wq = ipw + (size_t)t * D_;
    float acc = ipb[t];
    for (int d = 0; d < D_; d++) acc += srow[d] * wq[d];
    qrow[t] = acc * 0.17677669529663689f;  // 1/sqrt(32)
  }
  __syncthreads();
  float qsum = 0.f;
  for (int h = 0; h < NHEAD; h++) {
    const float* wkbase = ipw + (size_t)(D_ + h * 32) * D_ + t;
    float a = 0.f;
    for (int e = 0; e < 32; e++) a += qrow[h * 32 + e] * wkbase[(size_t)e * D_];
    qk_g[((size_t)s * NHEAD + h) * D_ + t] = a;
    qsum += a;
  }
  qksum_g[s * D_ + t] = qsum;
  if (t < NHEAD) {
    float a = 0.f;
    for (int e = 0; e < 32; e++) a += qrow[t * 32 + e] * ipb[D_ + t * 32 + e];
    qbk_g[s * NHEAD + t] = a;
  }
}

// ---------------- Kernel C (bf16): aff + fused PV partials, DMA ring, packed kpf ----------------
// grid = (slot, half), 512 thr. Wave w: 40 steps:
//   step i<32: pos row w*32+i (one 1KB kpf row: kp|f) -> aff+PV     (1 size-16 DMA)
//   step i>=32: TWO neg rows 256+w*16+2(i-32), +1 (kp halves only)  (4 size-4 DMAs)
// 2-slot ring; counted vmcnt: pos phase vmcnt(1), neg phase vmcnt(4).
__global__ __launch_bounds__(512, 2) void aff_pv_bf16_kernel(
    const unsigned short* __restrict__ kpf,
    const int* __restrict__ batch_idx, const int* __restrict__ feat_sel,
    const float* __restrict__ qk_g, const float* __restrict__ qbk_g,
    const float* __restrict__ qksum_g,
    float* __restrict__ fbar_part,    // [256][2][8][256]
    float* __restrict__ expsum_part,  // [256][2][8]
    float* __restrict__ stat_part,    // [256][2][2]
    float* __restrict__ aff2_g) {     // [256][768]
  __shared__ unsigned int ring[8][2][256]; // 16 KB: [wave][slot][1KB]
  __shared__ float qks[NHEAD][D_];    // 8 KB
  __shared__ float fbar[NHEAD][D_];   // 8 KB
  __shared__ float a2buf[384];        // 1.5 KB
  __shared__ int   sfsel[384];        // 1.5 KB
  __shared__ float wtile[8][NHEAD];
  __shared__ float esums[8][NHEAD];
  __shared__ float sstat[8][2];
  __shared__ float qbkmean_s;

  int b = blockIdx.x, s = b >> 1, half = b & 1;
  int t = threadIdx.x, w = t >> 6, lane = t & 63;
  int bi = batch_idx[s];

  for (int i = t; i < NHEAD * D_; i += 512) {
    ((float*)qks)[i] = qk_g[(size_t)s * (NHEAD * D_) + i];
    ((float*)fbar)[i] = 0.f;
  }
  if (t < 384) sfsel[t] = feat_sel[s * NSEL + half + 2 * t];
  if (t == 0) {
    float m = 0.f;
    for (int h = 0; h < NHEAD; h++) m += qbk_g[s * NHEAD + h];
    qbkmean_s = m * 0.125f;
  }
  __syncthreads();
  float qbkmean = qbkmean_s;
  const float4 qs4 = *(const float4*)&qksum_g[s * D_ + lane * 4];
  int lane4 = lane * 4;

  float acc[NHEAD][4];
#pragma unroll
  for (int h = 0; h < NHEAD; h++)
#pragma unroll
    for (int c = 0; c < 4; c++) acc[h][c] = 0.f;
  float esum = 0.f;  // lanes with (lane&7)==0; head = lane>>3

  // PER-LANE global source offsets (the R12 bug): 16B/lane -> +lane*8 ushorts,
  // 4B/lane -> +lane*2 ushorts.
  auto ISSUE_POS = [&](int j, int slot) {
    int r = w * 32 + j;
    const unsigned short* s0 = kpf + (size_t)(sfsel[r] * BB + bi) * 512 + lane * 8;
    GLD16(s0, &ring[w][slot][0]);
  };
  auto ISSUE_NEG = [&](int j, int slot) {
    int r0 = 256 + w * 16 + 2 * (j - 32);
    const unsigned short* s0 = kpf + (size_t)(sfsel[r0] * BB + bi) * 512 + lane * 2;
    const unsigned short* s1 = kpf + (size_t)(sfsel[r0 + 1] * BB + bi) * 512 + lane * 2;
    unsigned int* d = &ring[w][slot][0];
    GLD4(s0, d);        GLD4(s0 + 128, d + 64);
    GLD4(s1, d + 128);  GLD4(s1 + 128, d + 192);
  };

  auto BODYP = [&](int i, int slot) {
    uint2 kpu = *(uint2*)&ring[w][slot][2 * lane];        // kp dims 4l..4l+3
    uint2 fu  = *(uint2*)&ring[w][slot][128 + 2 * lane];  // f  dims 4l..4l+3
    asm volatile("s_waitcnt lgkmcnt(0)" ::: "memory");    // ring reads done before reuse
    if (i + 2 < 32) ISSUE_POS(i + 2, slot); else ISSUE_NEG(i + 2, slot);
    float k0 = BFLO(kpu.x), k1 = BFHI(kpu.x), k2 = BFLO(kpu.y), k3 = BFHI(kpu.y);
    float f0 = BFLO(fu.x),  f1 = BFHI(fu.x),  f2 = BFLO(fu.y),  f3 = BFHI(fu.y);
    int r = w * 32 + i;
    float pp[NHEAD];
#pragma unroll
    for (int h = 0; h < NHEAD; h++) {
      const float4 qw = *(const float4*)&qks[h][lane4];
      pp[h] = k0 * qw.x + k1 * qw.y + k2 * qw.z + k3 * qw.w;
    }
    float rs = reduce8x64(pp, lane);
    float e = __expf(rs);
    if ((lane & 7) == 0) {
      wtile[w][lane >> 3] = e;
      esum += e;
    }
    float ts = rs;
    ts += __shfl_xor(ts, 8, 64);
    ts += __shfl_xor(ts, 16, 64);
    ts += __shfl_xor(ts, 32, 64);
    if (lane == 0) a2buf[r] = ts * 0.125f + qbkmean;
    const float4 w0 = *(const float4*)&wtile[w][0];
    const float4 w1 = *(const float4*)&wtile[w][4];
    acc[0][0] += w0.x * f0; acc[0][1] += w0.x * f1; acc[0][2] += w0.x * f2; acc[0][3] += w0.x * f3;
    acc[1][0] += w0.y * f0; acc[1][1] += w0.y * f1; acc[1][2] += w0.y * f2; acc[1][3] += w0.y * f3;
    acc[2][0] += w0.z * f0; acc[2][1] += w0.z * f1; acc[2][2] += w0.z * f2; acc[2][3] += w0.z * f3;
    acc[3][0] += w0.w * f0; acc[3][1] += w0.w * f1; acc[3][2] += w0.w * f2; acc[3][3] += w0.w * f3;
    acc[4][0] += w1.x * f0; acc[4][1] += w1.x * f1; acc[4][2] += w1.x * f2; acc[4][3] += w1.x * f3;
    acc[5][0] += w1.y * f0; acc[5][1] += w1.y * f1; acc[5][2] += w1.y * f2; acc[5][3] += w1.y * f3;
    acc[6][0] += w1.z * f0; acc[6][1] += w1.z * f1; acc[6][2] += w1.z * f2; acc[6][3] += w1.z * f3;
    acc[7][0] += w1.w * f0; acc[7][1] += w1.w * f1; acc[7][2] += w1.w * f2; acc[7][3] += w1.w * f3;
  };

  auto BODYN = [&](int i, int slot) {
    uint2 a0 = *(uint2*)&ring[w][slot][2 * lane];        // row0 kp dims 4l..4l+3
    uint2 a1 = *(uint2*)&ring[w][slot][128 + 2 * lane];  // row1 kp dims 4l..4l+3
    asm volatile("s_waitcnt lgkmcnt(0)" ::: "memory");
    if (i + 2 < 40) ISSUE_NEG(i + 2, slot);
    float x0 = BFLO(a0.x), x1 = BFHI(a0.x), x2 = BFLO(a0.y), x3 = BFHI(a0.y);
    float y0 = BFLO(a1.x), y1 = BFHI(a1.x), y2 = BFLO(a1.y), y3 = BFHI(a1.y);
    float spp0 = x0 * qs4.x + x1 * qs4.y + x2 * qs4.z + x3 * qs4.w;
    float spp1 = y0 * qs4.x + y1 * qs4.y + y2 * qs4.z + y3 * qs4.w;
#pragma unroll
    for (int off = 1; off < 64; off <<= 1) {
      spp0 += __shfl_xor(spp0, off, 64);
      spp1 += __shfl_xor(spp1, off, 64);
    }
    if (lane == 0) {
      int r0 = 256 + w * 16 + 2 * (i - 32);
      a2buf[r0] = spp0 * 0.125f + qbkmean;
      a2buf[r0 + 1] = spp1 * 0.125f + qbkmean;
    }
  };

#define WV(n) asm volatile("s_waitcnt vmcnt(" #n ")" ::: "memory")
  // prologue: steps 0,1 (1 op each)
  ISSUE_POS(0, 0);
  ISSUE_POS(1, 1);
  // pos bodies 0..29 (issue pos steps 2..31)
  for (int i0 = 0; i0 < 30; i0 += 2) {
    WV(1); BODYP(i0, 0);
    WV(1); BODYP(i0 + 1, 1);
  }
  WV(1); BODYP(30, 0);   // issues neg step 32 (4 ops)
  WV(4); BODYP(31, 1);   // issues neg step 33
  // neg bodies 32..37 (issue 34..39)
  for (int i0 = 32; i0 < 38; i0 += 2) {
    WV(4); BODYN(i0, 0);
    WV(4); BODYN(i0 + 1, 1);
  }
  WV(4); BODYN(38, 0);   // nothing left to issue
  WV(0); BODYN(39, 1);
#undef WV

  // ---- combine partials
  if ((lane & 7) == 0) esums[w][lane >> 3] = esum;
#pragma unroll
  for (int h = 0; h < NHEAD; h++) {
    atomicAdd(&fbar[h][lane4 + 0], acc[h][0]);
    atomicAdd(&fbar[h][lane4 + 1], acc[h][1]);
    atomicAdd(&fbar[h][lane4 + 2], acc[h][2]);
    atomicAdd(&fbar[h][lane4 + 3], acc[h][3]);
  }
  __syncthreads();
  {
    float v = (t < 384) ? a2buf[t] : 0.f;
    float ls = v, lq = v * v;
#pragma unroll
    for (int off = 32; off >= 1; off >>= 1) { ls += __shfl_xor(ls, off, 64); lq += __shfl_xor(lq, off, 64); }
    if (lane == 0) { sstat[w][0] = ls; sstat[w][1] = lq; }
  }
  __syncthreads();
  if (t < NHEAD) {
    float e2 = 0.f;
    for (int w2 = 0; w2 < 8; w2++) e2 += esums[w2][t];
    expsum_part[b * NHEAD + t] = e2;
  } else if (t == NHEAD) {
    float a = 0.f, q = 0.f;
    for (int w2 = 0; w2 < 8; w2++) { a += sstat[w2][0]; q += sstat[w2][1]; }
    stat_part[b * 2 + 0] = a;
    stat_part[b * 2 + 1] = q;
  }
  if (t < 384) aff2_g[s * NSEL + half + 2 * t] = a2buf[t];
  ((float4*)(fbar_part + (size_t)b * (NHEAD * D_)))[t] = ((float4*)fbar)[t];
}

// ---------------- Kernel C (fp32 fallback, R11-proven): used if ws too small ----------------
__global__ __launch_bounds__(512, 2) void aff_pv_f32_kernel(
    const float* __restrict__ features, const float* __restrict__ posenc,
    const int* __restrict__ batch_idx, const int* __restrict__ feat_sel,
    const float* __restrict__ qk_g, const float* __restrict__ qbk_g,
    const float* __restrict__ qksum_g,
    float* __restrict__ fbar_part, float* __restrict__ expsum_part,
    float* __restrict__ stat_part, float* __restrict__ aff2_g) {
  __shared__ float ring[8][2][2][D_];
  __shared__ float qks[NHEAD][D_];
  __shared__ float fbar[NHEAD][D_];
  __shared__ float a2buf[384];
  __shared__ int   sfsel[384];
  __shared__ float wtile[8][NHEAD];
  __shared__ float esums[8][NHEAD];
  __shared__ float sstat[8][2];
  __shared__ float qbkmean_s;

  int b = blockIdx.x, s = b >> 1, half = b & 1;
  int t = threadIdx.x, w = t >> 6, lane = t & 63;
  int bi = batch_idx[s];

  for (int i = t; i < NHEAD * D_; i += 512) {
    ((float*)qks)[i] = qk_g[(size_t)s * (NHEAD * D_) + i];
    ((float*)fbar)[i] = 0.f;
  }
  if (t < 384) sfsel[t] = feat_sel[s * NSEL + half + 2 * t];
  if (t == 0) {
    float m = 0.f;
    for (int h = 0; h < NHEAD; h++) m += qbk_g[s * NHEAD + h];
    qbkmean_s = m * 0.125f;
  }
  __syncthreads();
  float qbkmean = qbkmean_s;
  const float4 qs4 = *(const float4*)&qksum_g[s * D_ + lane * 4];
  size_t lofs = (size_t)(lane * 4);
  int lane4 = lane * 4;

  float acc[NHEAD][4];
#pragma unroll
  for (int h = 0; h < NHEAD; h++)
#pragma unroll
    for (int c = 0; c < 4; c++) acc[h][c] = 0.f;
  float esum = 0.f;

  auto ISSUE = [&](int j, int slot) {
    int r = (j < 32) ? (w * 32 + j) : (256 + w * 16 + (j - 32));
    size_t gb = ((size_t)sfsel[r] * BB + bi) * D_ + lofs;
    GLD16(features + gb, &ring[w][slot][0][0]);
    GLD16(posenc + gb, &ring[w][slot][1][0]);
  };
  auto BODY = [&](int i, int slot) {
    const float4 f = *(const float4*)&ring[w][slot][0][lane4];
    const float4 p = *(const float4*)&ring[w][slot][1][lane4];
    float4 k;
    k.x = f.x + p.x; k.y = f.y + p.y; k.z = f.z + p.z; k.w = f.w + p.w;
    asm volatile("" ::: "memory");
    if (i + 2 < 48) ISSUE(i + 2, slot);
    if (i < 32) {
      int r = w * 32 + i;
      float pp[NHEAD];
#pragma unroll
      for (int h = 0; h < NHEAD; h++) {
        const float4 qw = *(const float4*)&qks[h][lane4];
        pp[h] = k.x * qw.x + k.y * qw.y + k.z * qw.z + k.w * qw.w;
      }
      float rs = reduce8x64(pp, lane);
      float e = __expf(rs);
      if ((lane & 7) == 0) {
        wtile[w][lane >> 3] = e;
        esum += e;
      }
      float ts = rs;
      ts += __shfl_xor(ts, 8, 64);
      ts += __shfl_xor(ts, 16, 64);
      ts += __shfl_xor(ts, 32, 64);
      if (lane == 0) a2buf[r] = ts * 0.125f + qbkmean;
      const float4 w0 = *(const float4*)&wtile[w][0];
      const float4 w1 = *(const float4*)&wtile[w][4];
      acc[0][0] += w0.x * f.x; acc[0][1] += w0.x * f.y; acc[0][2] += w0.x * f.z; acc[0][3] += w0.x * f.w;
      acc[1][0] += w0.y * f.x; acc[1][1] += w0.y * f.y; acc[1][2] += w0.y * f.z; acc[1][3] += w0.y * f.w;
      acc[2][0] += w0.z * f.x; acc[2][1] += w0.z * f.y; acc[2][2] += w0.z * f.z; acc[2][3] += w0.z * f.w;
      acc[3][0] += w0.w * f.x; acc[3][1] += w0.w * f.y; acc[3][2] += w0.w * f.z; acc[3][3] += w0.w * f.w;
      acc[4][0] += w1.x * f.x; acc[4][1] += w1.x * f.y; acc[4][2] += w1.x * f.z; acc[4][3] += w1.x * f.w;
      acc[5][0] += w1.y * f.x; acc[5][1] += w1.y * f.y; acc[5][2] += w1.y * f.z; acc[5][3] += w1.y * f.w;
      acc[6][0] += w1.z * f.x; acc[6][1] += w1.z * f.y; acc[6][2] += w1.z * f.z; acc[6][3] += w1.z * f.w;
      acc[7][0] += w1.w * f.x; acc[7][1] += w1.w * f.y; acc[7][2] += w1.w * f.z; acc[7][3] += w1.w * f.w;
    } else {
      int r = 256 + w * 16 + (i - 32);
      float spp = k.x * qs4.x + k.y * qs4.y + k.z * qs4.z + k.w * qs4.w;
#pragma unroll
      for (int off = 1; off < 64; off <<= 1) spp += __shfl_xor(spp, off, 64);
      if (lane == 0) a2buf[r] = spp * 0.125f + qbkmean;
    }
  };

  ISSUE(0, 0);
  ISSUE(1, 1);
  for (int i0 = 0; i0 < 46; i0 += 2) {
    asm volatile("s_waitcnt vmcnt(2)" ::: "memory");
    BODY(i0, 0);
    asm volatile("s_waitcnt vmcnt(2)" ::: "memory");
    BODY(i0 + 1, 1);
  }
  asm volatile("s_waitcnt vmcnt(2)" ::: "memory");
  BODY(46, 0);
  asm volatile("s_waitcnt vmcnt(0)" ::: "memory");
  BODY(47, 1);

  if ((lane & 7) == 0) esums[w][lane >> 3] = esum;
#pragma unroll
  for (int h = 0; h < NHEAD; h++) {
    atomicAdd(&fbar[h][lane4 + 0], acc[h][0]);
    atomicAdd(&fbar[h][lane4 + 1], acc[h][1]);
    atomicAdd(&fbar[h][lane4 + 2], acc[h][2]);
    atomicAdd(&fbar[h][lane4 + 3], acc[h][3]);
  }
  __syncthreads();
  {
    float v = (t < 384) ? a2buf[t] : 0.f;
    float ls = v, lq = v * v;
#pragma unroll
    for (int off = 32; off >= 1; off >>= 1) { ls += __shfl_xor(ls, off, 64); lq += __shfl_xor(lq, off, 64); }
    if (lane == 0) { sstat[w][0] = ls; sstat[w][1] = lq; }
  }
  __syncthreads();
  if (t < NHEAD) {
    float e2 = 0.f;
    for (int w2 = 0; w2 < 8; w2++) e2 += esums[w2][t];
    expsum_part[b * NHEAD + t] = e2;
  } else if (t == NHEAD) {
    float a = 0.f, q = 0.f;
    for (int w2 = 0; w2 < 8; w2++) { a += sstat[w2][0]; q += sstat[w2][1]; }
    stat_part[b * 2 + 0] = a;
    stat_part[b * 2 + 1] = q;
  }
  if (t < 384) aff2_g[s * NSEL + half + 2 * t] = a2buf[t];
  ((float4*)(fbar_part + (size_t)b * (NHEAD * D_)))[t] = ((float4*)fbar)[t];
}

// ---------------- Kernel D: combine partials + Wv + out-proj + LN + norm_aff ----------------
__global__ __launch_bounds__(1024) void finish_kernel(
    const float* __restrict__ slots,
    const float* __restrict__ expsum_part, const float* __restrict__ stat_part,
    const float* __restrict__ aff2_g, const float* __restrict__ fbar_part,
    const float* __restrict__ ipw, const float* __restrict__ ipb,
    const float* __restrict__ wout, const float* __restrict__ bout,
    const float* __restrict__ lnw, const float* __restrict__ lnb,
    float* __restrict__ slots_new, float* __restrict__ norm_aff) {
  __shared__ float fbar[NHEAD][D_];
  __shared__ float srow[D_];
  __shared__ float outv[D_];
  __shared__ float pq[1024];
  __shared__ float redS[4], redQ[4];
  int s = blockIdx.x, t = threadIdx.x, wave = t >> 6, lane = t & 63;

  float st0 = stat_part[s * 4 + 0] + stat_part[s * 4 + 2];
  float st1 = stat_part[s * 4 + 1] + stat_part[s * 4 + 3];
  float mean_a = st0 * (1.0f / NSEL);
  float var_a = st1 * (1.0f / NSEL) - mean_a * mean_a;
  float rstd_a = rsqrtf(var_a + 1e-5f);
  if (t < NSEL) norm_aff[(size_t)t * NSLOT + s] = (aff2_g[s * NSEL + t] - mean_a) * rstd_a;

  if (t < 512) {
    int h = t >> 6;  // fbar layout [8][256]: 64 float4s per head
    float inv = 1.0f / (expsum_part[s * 16 + h] + expsum_part[s * 16 + 8 + h]);
    const float4 a = ((const float4*)(fbar_part + (size_t)s * 4096))[t];
    const float4 c = ((const float4*)(fbar_part + (size_t)s * 4096 + 2048))[t];
    float4 r;
    r.x = (a.x + c.x) * inv; r.y = (a.y + c.y) * inv;
    r.z = (a.z + c.z) * inv; r.w = (a.w + c.w) * inv;
    ((float4*)fbar)[t] = r;
  }
  if (t < 64) ((float4*)srow)[t] = ((const float4*)(slots + (size_t)s * D_))[t];
  __syncthreads();

  {
    int o = t >> 2, part = t & 3, h = o >> 5;
    const float4* wv = (const float4*)(ipw + (size_t)(2 * D_ + o) * D_ + part * 64);
    float a = 0.f;
#pragma unroll
    for (int i = 0; i < 16; i++) {
      float4 w = wv[i];
      int d = part * 64 + i * 4;
      a += fbar[h][d] * w.x + fbar[h][d + 1] * w.y + fbar[h][d + 2] * w.z + fbar[h][d + 3] * w.w;
    }
    pq[t] = a;
  }
  __syncthreads();
  if (t < D_)
    outv[t] = pq[t * 4] + pq[t * 4 + 1] + pq[t * 4 + 2] + pq[t * 4 + 3] + ipb[2 * D_ + t];
  __syncthreads();

  {
    int o = t >> 2, part = t & 3;
    const float4* w4 = (const float4*)(wout + (size_t)o * D_ + part * 64);
    float a = 0.f;
#pragma unroll
    for (int i = 0; i < 16; i++) {
      float4 w = w4[i];
      int d = part * 64 + i * 4;
      a += outv[d] * w.x + outv[d + 1] * w.y + outv[d + 2] * w.z + outv[d + 3] * w.w;
    }
    pq[t] = a;
  }
  __syncthreads();
  float v = 0.f;
  if (t < D_) {
    v = srow[t] + pq[t * 4] + pq[t * 4 + 1] + pq[t * 4 + 2] + pq[t * 4 + 3] + bout[t];
    float ls = v, lq = v * v;
#pragma unroll
    for (int off = 32; off >= 1; off >>= 1) { ls += __shfl_xor(ls, off, 64); lq += __shfl_xor(lq, off, 64); }
    if (lane == 0) { redS[wave] = ls; redQ[wave] = lq; }
  }
  __syncthreads();
  if (t < D_) {
    float tots = redS[0] + redS[1] + redS[2] + redS[3];
    float totq = redQ[0] + redQ[1] + redQ[2] + redQ[3];
    float mean = tots * (1.0f / D_);
    float var = totq * (1.0f / D_) - mean * mean;
    float rstd = rsqrtf(var + 1e-5f);
    slots_new[s * D_ + t] = (v - mean) * rstd * lnw[t] + lnb[t];
  }
}

extern "C" void kernel_launch(void* const* d_in, const int* in_sizes, int n_in,
                              void* d_out, int out_size, void* d_ws, size_t ws_size,
                              hipStream_t stream) {
  const float* slots    = (const float*)d_in[0];
  const float* features = (const float*)d_in[1];
  const float* posenc   = (const float*)d_in[2];
  const float* curio    = (const float*)d_in[3];
  const int*   batch_idx= (const int*)d_in[4];
  const float* ipw      = (const float*)d_in[5];
  const float* ipb      = (const float*)d_in[6];
  const float* wout     = (const float*)d_in[7];
  const float* bout     = (const float*)d_in[8];
  const float* lnw      = (const float*)d_in[9];
  const float* lnb      = (const float*)d_in[10];

  char* ws = (char*)d_ws;
  size_t off = 0;
  int*   feat_sel    = (int*)(ws + off);   off += 256 * 768 * 4;        // 786432
  float* qk_g        = (float*)(ws + off); off += 256 * 8 * 256 * 4;    // 2097152
  float* qbk_g       = (float*)(ws + off); off += 256 * 8 * 4;          // 8192
  float* qksum_g     = (float*)(ws + off); off += 256 * 256 * 4;        // 262144
  float* fbar_part   = (float*)(ws + off); off += 256 * 2 * 8 * 256 * 4;// 4194304
  float* expsum_part = (float*)(ws + off); off += 256 * 2 * 8 * 4;      // 16384
  float* stat_part   = (float*)(ws + off); off += 256 * 2 * 2 * 4;      // 4096
  float* aff2_g      = (float*)(ws + off); off += 256 * 768 * 4;        // 786432
  size_t kpf_off = (off + 1023) & ~(size_t)1023;
  unsigned short* kpf = (unsigned short*)(ws + kpf_off);                // 67108864
  bool use_bf16 = (ws_size >= kpf_off + (size_t)HWN * BB * 512 * 2);

  float* out_f = (float*)d_out;  // [0,65536) slots_new, [65536,262144) norm_aff

  if (use_bf16)
    pack_kernel<<<2048, 256, 0, stream>>>(features, posenc, kpf);
  topk_kernel<<<NSLOT, 1024, 0, stream>>>(curio, feat_sel);
  qproj_kernel<<<NSLOT, 256, 0, stream>>>(slots, ipw, ipb, qk_g, qbk_g, qksum_g);
  if (use_bf16)
    aff_pv_bf16_kernel<<<NSLOT * 2, 512, 0, stream>>>(kpf, batch_idx, feat_sel,
                                                      qk_g, qbk_g, qksum_g, fbar_part,
                                                      expsum_part, stat_part, aff2_g);
  else
    aff_pv_f32_kernel<<<NSLOT * 2, 512, 0, stream>>>(features, posenc, batch_idx, feat_sel,
                                                     qk_g, qbk_g, qksum_g, fbar_part,
                                                     expsum_part, stat_part, aff2_g);
  finish_kernel<<<NSLOT, 1024, 0, stream>>>(slots, expsum_part, stat_part, aff2_g,
                                            fbar_part, ipw, ipb, wout, bout, lnw, lnb,
                                            out_f, out_f + 65536);
}

// Round 14
// 161.967 us; speedup vs baseline: 1.1996x; 1.1996x over previous
//
#include <hip/hip_runtime.h>
#include <math.h>

#define NSLOT 256
#define HWN   16384
#define D_    256
#define BB    4
#define NSEL  768
#define NPOS  512
#define NHEAD 8

typedef __attribute__((ext_vector_type(8))) short short8v;   // 8 bf16 (4 VGPRs)
typedef __attribute__((ext_vector_type(4))) float float4v;   // MFMA C/D

// global->LDS DMA: size B per lane; LDS dest wave-uniform base; GLOBAL SOURCE PER-LANE.
#define GLD16(g, l)                                                        \
  __builtin_amdgcn_global_load_lds(                                        \
      (__attribute__((address_space(1))) void*)(g),                        \
      (__attribute__((address_space(3))) void*)(l), 16, 0, 0)
#define GLD4(g, l)                                                         \
  __builtin_amdgcn_global_load_lds(                                        \
      (__attribute__((address_space(1))) void*)(g),                        \
      (__attribute__((address_space(3))) void*)(l), 4, 0, 0)

#define BFLO(u) __uint_as_float((u) << 16)
#define BFHI(u) __uint_as_float((u) & 0xffff0000u)

__device__ __forceinline__ unsigned short f2bf(float x) {   // RNE bf16
  unsigned u = __float_as_uint(x);
  unsigned r = u + 0x7fffu + ((u >> 16) & 1u);
  return (unsigned short)(r >> 16);
}
__device__ __forceinline__ unsigned int pk2(float a, float b) {
  return (unsigned)f2bf(a) | ((unsigned)f2bf(b) << 16);
}

// Reduce 8 per-lane values over all 64 lanes simultaneously (f32 fallback only).
__device__ __forceinline__ float reduce8x64(const float p[8], int lane) {
  float v[4];
#pragma unroll
  for (int h = 0; h < 4; h++) {
    float keep = (lane & 32) ? p[h + 4] : p[h];
    float send = (lane & 32) ? p[h] : p[h + 4];
    v[h] = keep + __shfl_xor(send, 32, 64);
  }
  float w[2];
#pragma unroll
  for (int h = 0; h < 2; h++) {
    float keep = (lane & 16) ? v[h + 2] : v[h];
    float send = (lane & 16) ? v[h] : v[h + 2];
    w[h] = keep + __shfl_xor(send, 16, 64);
  }
  float r;
  {
    float keep = (lane & 8) ? w[1] : w[0];
    float send = (lane & 8) ? w[0] : w[1];
    r = keep + __shfl_xor(send, 8, 64);
  }
  r += __shfl_xor(r, 4, 64);
  r += __shfl_xor(r, 2, 64);
  r += __shfl_xor(r, 1, 64);
  return r;
}

// ---------------- Kernel P: pack kpf[row][0:256]=bf16(f+p), [256:512]=bf16(f) ----------------
__global__ __launch_bounds__(256) void pack_kernel(const float* __restrict__ f,
                                                   const float* __restrict__ p,
                                                   unsigned short* __restrict__ kpf) {
  int stride = gridDim.x * 256;
  for (int u = blockIdx.x * 256 + threadIdx.x; u < HWN * BB * 32; u += stride) {
    int row = u >> 5, c8 = (u & 31) << 3;
    const float4* f4 = (const float4*)(f + (size_t)row * D_ + c8);
    const float4* p4 = (const float4*)(p + (size_t)row * D_ + c8);
    float4 a0 = f4[0], a1 = f4[1], b0 = p4[0], b1 = p4[1];
    uint4 kp, ff;
    kp.x = pk2(a0.x + b0.x, a0.y + b0.y);
    kp.y = pk2(a0.z + b0.z, a0.w + b0.w);
    kp.z = pk2(a1.x + b1.x, a1.y + b1.y);
    kp.w = pk2(a1.z + b1.z, a1.w + b1.w);
    ff.x = pk2(a0.x, a0.y); ff.y = pk2(a0.z, a0.w);
    ff.z = pk2(a1.x, a1.y); ff.w = pk2(a1.z, a1.w);
    *(uint4*)(kpf + (size_t)row * 512 + c8) = kp;
    *(uint4*)(kpf + (size_t)row * 512 + 256 + c8) = ff;
  }
}

// ---------------- Kernel A: per-slot top-768 stable select (1024 thr) ----------------
__global__ __launch_bounds__(1024) void topk_kernel(const float* __restrict__ curio,
                                                    int* __restrict__ feat_sel) {
  __shared__ unsigned int hist[4096];
  __shared__ unsigned int wsum[16];
  __shared__ unsigned long long skey[2048];
  __shared__ int sBstar;
  __shared__ unsigned int sCount;
  int s = blockIdx.x;
  int t = threadIdx.x;
  int wave = t >> 6, lane = t & 63;
  const float* row = curio + (size_t)s * HWN;

  for (int i = t; i < 4096; i += 1024) hist[i] = 0;
  if (t == 0) sCount = 0;
  __syncthreads();
  for (int j = t; j < HWN; j += 1024) {
    unsigned int bits = __float_as_uint(row[j]);   // values in [0,1): bits monotone
    atomicAdd(&hist[bits >> 18], 1u);
  }
  __syncthreads();
  unsigned int cs = hist[t * 4] + hist[t * 4 + 1] + hist[t * 4 + 2] + hist[t * 4 + 3];
  unsigned int v = cs;
#pragma unroll
  for (int off = 1; off < 64; off <<= 1) {
    unsigned int u = __shfl_down(v, off, 64);
    if (lane + off < 64) v += u;       // suffix over lanes >= lane (this wave)
  }
  if (lane == 0) wsum[wave] = v;
  __syncthreads();
  unsigned int above = 0;
  for (int w2 = wave + 1; w2 < 16; w2++) above += wsum[w2];
  unsigned int sufAfter = above + (v - cs);
  if (sufAfter < NSEL && sufAfter + cs >= NSEL) {
    unsigned int local = sufAfter;
    for (int b = t * 4 + 3; b >= t * 4; b--) {
      unsigned int c = hist[b];
      if (local + c >= NSEL) { sBstar = b; break; }
      local += c;
    }
  }
  __syncthreads();
  int bstar = sBstar;
  for (int j = t; j < HWN; j += 1024) {
    unsigned int bits = __float_as_uint(row[j]);
    if ((int)(bits >> 18) >= bstar) {
      unsigned int pos = atomicAdd(&sCount, 1u);
      if (pos < 2048)
        skey[pos] = ((unsigned long long)bits << 14) | (unsigned long long)(16383 - j);
    }
  }
  __syncthreads();
  unsigned int M = sCount;
  int SZ = (M <= 1024) ? 1024 : 2048;
  for (int i = t; i < SZ; i += 1024) if (i >= (int)M) skey[i] = 0ull;
  for (int k = 2; k <= SZ; k <<= 1) {
    for (int j2 = k >> 1; j2 > 0; j2 >>= 1) {
      __syncthreads();
      for (int i = t; i < SZ; i += 1024) {
        int l = i ^ j2;
        if (l > i) {
          unsigned long long a = skey[i], b = skey[l];
          bool dir = ((i & k) == 0);
          if ((a < b) == dir) { skey[i] = b; skey[l] = a; }
        }
      }
    }
  }
  __syncthreads();
  for (int r = t; r < NSEL; r += 1024)
    feat_sel[s * NSEL + r] = 16383 - (int)(skey[r] & 16383ull);
}

// ---------------- Kernel B: q proj + qk + qksum + qkb16 (MFMA B-frags) ----------------
__global__ __launch_bounds__(256) void qproj_kernel(const float* __restrict__ slots,
                                                    const float* __restrict__ ipw,
                                                    const float* __restrict__ ipb,
                                                    float* __restrict__ qk_g,
                                                    float* __restrict__ qbk_g,
                                                    float* __restrict__ qksum_g,
                                                    unsigned short* __restrict__ qkb16) {
  __shared__ float srow[D_];
  __shared__ float qrow[D_];
  __shared__ float qkl[NHEAD][D_];
  __shared__ float qsl[D_];
  int s = blockIdx.x, t = threadIdx.x;
  srow[t] = slots[s * D_ + t];
  __syncthreads();
  {
    const float* wq = ipw + (size_t)t * D_;
    float acc = ipb[t];
    for (int d = 0; d < D_; d++) acc += srow[d] * wq[d];
    qrow[t] = acc * 0.17677669529663689f;  // 1/sqrt(32)
  }
  __syncthreads();
  float qsum = 0.f;
  for (int h = 0; h < NHEAD; h++) {
    const float* wkbase = ipw + (size_t)(D_ + h * 32) * D_ + t;
    float a = 0.f;
    for (int e = 0; e < 32; e++) a += qrow[h * 32 + e] * wkbase[(size_t)e * D_];
    qk_g[((size_t)s * NHEAD + h) * D_ + t] = a;
    qkl[h][t] = a;
    qsum += a;
  }
  qksum_g[s * D_ + t] = qsum;
  qsl[t] = qsum;
  if (t < NHEAD) {
    float a = 0.f;
    for (int e = 0; e < 32; e++) a += qrow[t * 32 + e] * ipb[D_ + t * 32 + e];
    qbk_g[s * NHEAD + t] = a;
  }
  __syncthreads();
  // qkb16[s][e], e = ((kc*64 + l)*8 + j): B-frag order. col=l&15; k=kc*32+((l>>4)&3)*8+j.
  // cols 0-7 = heads, col 8 = qksum, cols 9-15 = 0.
  for (int i = 0; i < 16; i++) {
    int e = t * 16 + i;
    int kc = e >> 9, l = (e >> 3) & 63, j = e & 7;
    int cc = l & 15, k = kc * 32 + ((l >> 4) & 3) * 8 + j;
    float v = (cc < NHEAD) ? qkl[cc][k] : ((cc == NHEAD) ? qsl[k] : 0.f);
    qkb16[(size_t)s * 4096 + e] = f2bf(v);
  }
}

// ---------------- Kernel C (MFMA): aff via matrix cores + scalar PV ----------------
// grid = (slot, half), 256 thr (4 waves). Wave w: 6 tiles of 16 rows:
// tiles 0-3 pos rows [w*64 .. w*64+64), tiles 4-5 neg rows 256+[w*32 .. +32).
// Per tile: DMA kp(16x528B) -> A-frags -> 8x mfma_f32_16x16x32_bf16 with
// B = qk bf16 (col 8 = qksum -> aff2 free) -> exp -> scalar PV (f from kpf to VGPR).
__global__ __launch_bounds__(256, 3) void aff_pv_mfma_kernel(
    const unsigned short* __restrict__ kpf,
    const unsigned short* __restrict__ qkb16,
    const int* __restrict__ batch_idx, const int* __restrict__ feat_sel,
    const float* __restrict__ qbk_g,
    float* __restrict__ fbar_part,    // [256][2][8][256]
    float* __restrict__ expsum_part,  // [256][2][8]
    float* __restrict__ stat_part,    // [256][2][2]
    float* __restrict__ aff2_g) {     // [256][768]
  __shared__ unsigned short kplds[4][16][264];  // 33 KB: per-wave 16 rows, 528B stride
  __shared__ unsigned short qkb[4096];          // 8 KB: [kc][lane][8] bf16 B-frags
  __shared__ float wlds[4][16][17];             // 4.3 KB: per-wave exp weights [n][h]
  __shared__ float fbar[NHEAD][D_];             // 8 KB
  __shared__ float a2buf[384];
  __shared__ int   sfsel[384];
  __shared__ float esums[4][NHEAD];
  __shared__ float sstat[4][2];
  __shared__ float qbkmean_s;

  int b = blockIdx.x, s = b >> 1, half = b & 1;
  int t = threadIdx.x, w = t >> 6, lane = t & 63;
  int bi = batch_idx[s];
  int col = lane & 15, quad = lane >> 4;

  {
    const uint4* src = (const uint4*)(qkb16 + (size_t)s * 4096);
    ((uint4*)qkb)[t] = src[t];
    ((uint4*)qkb)[t + 256] = src[t + 256];
  }
  for (int i = t; i < 384; i += 256) sfsel[i] = feat_sel[s * NSEL + half + 2 * i];
  for (int i = t; i < NHEAD * D_; i += 256) ((float*)fbar)[i] = 0.f;
  if (t == 0) {
    float m = 0.f;
    for (int h = 0; h < NHEAD; h++) m += qbk_g[s * NHEAD + h];
    qbkmean_s = m * 0.125f;
  }
  __syncthreads();

  unsigned short* kslot = &kplds[w][0][0];
  float acc[NHEAD][4];
#pragma unroll
  for (int h = 0; h < NHEAD; h++)
#pragma unroll
    for (int c = 0; c < 4; c++) acc[h][c] = 0.f;
  float esum_acc = 0.f;  // valid on lanes with col<8 (head=col)

  auto ISSUE_KP = [&](int L) {
#pragma unroll
    for (int r = 0; r < 16; r++) {
      const unsigned short* src =
          kpf + (size_t)((unsigned)sfsel[L + r] * BB + bi) * 512 + lane * 2;
      GLD4(src, kslot + r * 264);
      GLD4(src + 128, kslot + r * 264 + 128);
    }
  };

  ISSUE_KP(w * 64);  // prologue: tile 0
#pragma unroll 1
  for (int i = 0; i < 6; i++) {
    int L = (i < 4) ? (w * 64 + i * 16) : (256 + w * 32 + (i - 4) * 16);
    asm volatile("s_waitcnt vmcnt(0)" ::: "memory");  // kp_i landed
    bool pos = (i < 4);
    uint2 fu[16];
    if (pos) {
#pragma unroll
      for (int r = 0; r < 16; r++)
        fu[r] = *(const uint2*)(kpf + (size_t)((unsigned)sfsel[L + r] * BB + bi) * 512 +
                                256 + lane * 4);
    }
    // A-frags into regs: A[row=col][k = kc*32 + quad*8 + j]
    short8v afr[8];
#pragma unroll
    for (int kc = 0; kc < 8; kc++)
      afr[kc] = *(const short8v*)(kslot + (size_t)col * 264 + kc * 32 + quad * 8);
    asm volatile("s_waitcnt lgkmcnt(0)" ::: "memory");  // A reads done before slot reuse
    __builtin_amdgcn_sched_barrier(0);
    if (i < 5) {
      int Ln = (i < 3) ? (w * 64 + (i + 1) * 16) : (256 + w * 32 + (i - 3) * 16);
      ISSUE_KP(Ln);
    }
    float4v c = {0.f, 0.f, 0.f, 0.f};
#pragma unroll
    for (int kc = 0; kc < 8; kc++) {
      short8v bfr = *(const short8v*)&qkb[(kc * 64 + lane) * 8];
      c = __builtin_amdgcn_mfma_f32_16x16x32_bf16(afr[kc], bfr, c, 0, 0, 0);
    }
    // C: row n = quad*4+j (local row L+n), col: 0-7 heads, 8 = qksum-dot
    if (pos) {
      if (col < NHEAD) {
        float e0 = __expf(c[0]), e1 = __expf(c[1]), e2 = __expf(c[2]), e3 = __expf(c[3]);
        esum_acc += e0 + e1 + e2 + e3;
        wlds[w][quad * 4 + 0][col] = e0;
        wlds[w][quad * 4 + 1][col] = e1;
        wlds[w][quad * 4 + 2][col] = e2;
        wlds[w][quad * 4 + 3][col] = e3;
      } else if (col == NHEAD) {
        float qm = qbkmean_s;
#pragma unroll
        for (int j = 0; j < 4; j++) a2buf[L + quad * 4 + j] = c[j] * 0.125f + qm;
      }
      asm volatile("s_waitcnt lgkmcnt(0)" ::: "memory");  // wlds writes visible in-wave
      __builtin_amdgcn_sched_barrier(0);
#pragma unroll
      for (int r = 0; r < 16; r++) {
        const float4 w0 = *(const float4*)&wlds[w][r][0];
        const float4 w1 = *(const float4*)&wlds[w][r][4];
        float f0 = BFLO(fu[r].x), f1 = BFHI(fu[r].x), f2 = BFLO(fu[r].y), f3 = BFHI(fu[r].y);
        acc[0][0] += w0.x * f0; acc[0][1] += w0.x * f1; acc[0][2] += w0.x * f2; acc[0][3] += w0.x * f3;
        acc[1][0] += w0.y * f0; acc[1][1] += w0.y * f1; acc[1][2] += w0.y * f2; acc[1][3] += w0.y * f3;
        acc[2][0] += w0.z * f0; acc[2][1] += w0.z * f1; acc[2][2] += w0.z * f2; acc[2][3] += w0.z * f3;
        acc[3][0] += w0.w * f0; acc[3][1] += w0.w * f1; acc[3][2] += w0.w * f2; acc[3][3] += w0.w * f3;
        acc[4][0] += w1.x * f0; acc[4][1] += w1.x * f1; acc[4][2] += w1.x * f2; acc[4][3] += w1.x * f3;
        acc[5][0] += w1.y * f0; acc[5][1] += w1.y * f1; acc[5][2] += w1.y * f2; acc[5][3] += w1.y * f3;
        acc[6][0] += w1.z * f0; acc[6][1] += w1.z * f1; acc[6][2] += w1.z * f2; acc[6][3] += w1.z * f3;
        acc[7][0] += w1.w * f0; acc[7][1] += w1.w * f1; acc[7][2] += w1.w * f2; acc[7][3] += w1.w * f3;
      }
    } else {
      if (col == NHEAD) {
        float qm = qbkmean_s;
#pragma unroll
        for (int j = 0; j < 4; j++) a2buf[L + quad * 4 + j] = c[j] * 0.125f + qm;
      }
    }
  }

  // esum: combine quads (lanes h, h+16, h+32, h+48 all have col==h for h<8)
  esum_acc += __shfl_xor(esum_acc, 16, 64);
  esum_acc += __shfl_xor(esum_acc, 32, 64);
  if (lane < NHEAD) esums[w][lane] = esum_acc;
#pragma unroll
  for (int h = 0; h < NHEAD; h++) {
    atomicAdd(&fbar[h][lane * 4 + 0], acc[h][0]);
    atomicAdd(&fbar[h][lane * 4 + 1], acc[h][1]);
    atomicAdd(&fbar[h][lane * 4 + 2], acc[h][2]);
    atomicAdd(&fbar[h][lane * 4 + 3], acc[h][3]);
  }
  __syncthreads();

  {
    float v1 = a2buf[t];
    float v2 = (t < 128) ? a2buf[256 + t] : 0.f;
    float ls = v1 + v2, lq = v1 * v1 + v2 * v2;
#pragma unroll
    for (int off = 32; off >= 1; off >>= 1) { ls += __shfl_xor(ls, off, 64); lq += __shfl_xor(lq, off, 64); }
    if (lane == 0) { sstat[w][0] = ls; sstat[w][1] = lq; }
  }
  __syncthreads();
  if (t < NHEAD) {
    expsum_part[b * NHEAD + t] = esums[0][t] + esums[1][t] + esums[2][t] + esums[3][t];
  } else if (t == NHEAD) {
    stat_part[b * 2 + 0] = sstat[0][0] + sstat[1][0] + sstat[2][0] + sstat[3][0];
    stat_part[b * 2 + 1] = sstat[0][1] + sstat[1][1] + sstat[2][1] + sstat[3][1];
  }
  aff2_g[s * NSEL + half + 2 * t] = a2buf[t];
  if (t < 128) aff2_g[s * NSEL + half + 2 * (256 + t)] = a2buf[256 + t];
  ((float4*)(fbar_part + (size_t)b * 2048))[t] = ((float4*)fbar)[t];
  ((float4*)(fbar_part + (size_t)b * 2048))[t + 256] = ((float4*)fbar)[t + 256];
}

// ---------------- Kernel C (fp32 fallback, R11-proven): used if ws too small ----------------
__global__ __launch_bounds__(512, 2) void aff_pv_f32_kernel(
    const float* __restrict__ features, const float* __restrict__ posenc,
    const int* __restrict__ batch_idx, const int* __restrict__ feat_sel,
    const float* __restrict__ qk_g, const float* __restrict__ qbk_g,
    const float* __restrict__ qksum_g,
    float* __restrict__ fbar_part, float* __restrict__ expsum_part,
    float* __restrict__ stat_part, float* __restrict__ aff2_g) {
  __shared__ float ring[8][2][2][D_];
  __shared__ float qks[NHEAD][D_];
  __shared__ float fbar[NHEAD][D_];
  __shared__ float a2buf[384];
  __shared__ int   sfsel[384];
  __shared__ float wtile[8][NHEAD];
  __shared__ float esums[8][NHEAD];
  __shared__ float sstat[8][2];
  __shared__ float qbkmean_s;

  int b = blockIdx.x, s = b >> 1, half = b & 1;
  int t = threadIdx.x, w = t >> 6, lane = t & 63;
  int bi = batch_idx[s];

  for (int i = t; i < NHEAD * D_; i += 512) {
    ((float*)qks)[i] = qk_g[(size_t)s * (NHEAD * D_) + i];
    ((float*)fbar)[i] = 0.f;
  }
  if (t < 384) sfsel[t] = feat_sel[s * NSEL + half + 2 * t];
  if (t == 0) {
    float m = 0.f;
    for (int h = 0; h < NHEAD; h++) m += qbk_g[s * NHEAD + h];
    qbkmean_s = m * 0.125f;
  }
  __syncthreads();
  float qbkmean = qbkmean_s;
  const float4 qs4 = *(const float4*)&qksum_g[s * D_ + lane * 4];
  size_t lofs = (size_t)(lane * 4);
  int lane4 = lane * 4;

  float acc[NHEAD][4];
#pragma unroll
  for (int h = 0; h < NHEAD; h++)
#pragma unroll
    for (int c = 0; c < 4; c++) acc[h][c] = 0.f;
  float esum = 0.f;

  auto ISSUE = [&](int j, int slot) {
    int r = (j < 32) ? (w * 32 + j) : (256 + w * 16 + (j - 32));
    size_t gb = ((size_t)sfsel[r] * BB + bi) * D_ + lofs;
    GLD16(features + gb, &ring[w][slot][0][0]);
    GLD16(posenc + gb, &ring[w][slot][1][0]);
  };
  auto BODY = [&](int i, int slot) {
    const float4 f = *(const float4*)&ring[w][slot][0][lane4];
    const float4 p = *(const float4*)&ring[w][slot][1][lane4];
    float4 k;
    k.x = f.x + p.x; k.y = f.y + p.y; k.z = f.z + p.z; k.w = f.w + p.w;
    asm volatile("" ::: "memory");
    if (i + 2 < 48) ISSUE(i + 2, slot);
    if (i < 32) {
      int r = w * 32 + i;
      float pp[NHEAD];
#pragma unroll
      for (int h = 0; h < NHEAD; h++) {
        const float4 qw = *(const float4*)&qks[h][lane4];
        pp[h] = k.x * qw.x + k.y * qw.y + k.z * qw.z + k.w * qw.w;
      }
      float rs = reduce8x64(pp, lane);
      float e = __expf(rs);
      if ((lane & 7) == 0) {
        wtile[w][lane >> 3] = e;
        esum += e;
      }
      float ts = rs;
      ts += __shfl_xor(ts, 8, 64);
      ts += __shfl_xor(ts, 16, 64);
      ts += __shfl_xor(ts, 32, 64);
      if (lane == 0) a2buf[r] = ts * 0.125f + qbkmean;
      const float4 w0 = *(const float4*)&wtile[w][0];
      const float4 w1 = *(const float4*)&wtile[w][4];
      acc[0][0] += w0.x * f.x; acc[0][1] += w0.x * f.y; acc[0][2] += w0.x * f.z; acc[0][3] += w0.x * f.w;
      acc[1][0] += w0.y * f.x; acc[1][1] += w0.y * f.y; acc[1][2] += w0.y * f.z; acc[1][3] += w0.y * f.w;
      acc[2][0] += w0.z * f.x; acc[2][1] += w0.z * f.y; acc[2][2] += w0.z * f.z; acc[2][3] += w0.z * f.w;
      acc[3][0] += w0.w * f.x; acc[3][1] += w0.w * f.y; acc[3][2] += w0.w * f.z; acc[3][3] += w0.w * f.w;
      acc[4][0] += w1.x * f.x; acc[4][1] += w1.x * f.y; acc[4][2] += w1.x * f.z; acc[4][3] += w1.x * f.w;
      acc[5][0] += w1.y * f.x; acc[5][1] += w1.y * f.y; acc[5][2] += w1.y * f.z; acc[5][3] += w1.y * f.w;
      acc[6][0] += w1.z * f.x; acc[6][1] += w1.z * f.y; acc[6][2] += w1.z * f.z; acc[6][3] += w1.z * f.w;
      acc[7][0] += w1.w * f.x; acc[7][1] += w1.w * f.y; acc[7][2] += w1.w * f.z; acc[7][3] += w1.w * f.w;
    } else {
      int r = 256 + w * 16 + (i - 32);
      float spp = k.x * qs4.x + k.y * qs4.y + k.z * qs4.z + k.w * qs4.w;
#pragma unroll
      for (int off = 1; off < 64; off <<= 1) spp += __shfl_xor(spp, off, 64);
      if (lane == 0) a2buf[r] = spp * 0.125f + qbkmean;
    }
  };

  ISSUE(0, 0);
  ISSUE(1, 1);
  for (int i0 = 0; i0 < 46; i0 += 2) {
    asm volatile("s_waitcnt vmcnt(2)" ::: "memory");
    BODY(i0, 0);
    asm volatile("s_waitcnt vmcnt(2)" ::: "memory");
    BODY(i0 + 1, 1);
  }
  asm volatile("s_waitcnt vmcnt(2)" ::: "memory");
  BODY(46, 0);
  asm volatile("s_waitcnt vmcnt(0)" ::: "memory");
  BODY(47, 1);

  if ((lane & 7) == 0) esums[w][lane >> 3] = esum;
#pragma unroll
  for (int h = 0; h < NHEAD; h++) {
    atomicAdd(&fbar[h][lane4 + 0], acc[h][0]);
    atomicAdd(&fbar[h][lane4 + 1], acc[h][1]);
    atomicAdd(&fbar[h][lane4 + 2], acc[h][2]);
    atomicAdd(&fbar[h][lane4 + 3], acc[h][3]);
  }
  __syncthreads();
  {
    float v = (t < 384) ? a2buf[t] : 0.f;
    float ls = v, lq = v * v;
#pragma unroll
    for (int off = 32; off >= 1; off >>= 1) { ls += __shfl_xor(ls, off, 64); lq += __shfl_xor(lq, off, 64); }
    if (lane == 0) { sstat[w][0] = ls; sstat[w][1] = lq; }
  }
  __syncthreads();
  if (t < NHEAD) {
    float e2 = 0.f;
    for (int w2 = 0; w2 < 8; w2++) e2 += esums[w2][t];
    expsum_part[b * NHEAD + t] = e2;
  } else if (t == NHEAD) {
    float a = 0.f, q = 0.f;
    for (int w2 = 0; w2 < 8; w2++) { a += sstat[w2][0]; q += sstat[w2][1]; }
    stat_part[b * 2 + 0] = a;
    stat_part[b * 2 + 1] = q;
  }
  if (t < 384) aff2_g[s * NSEL + half + 2 * t] = a2buf[t];
  ((float4*)(fbar_part + (size_t)b * (NHEAD * D_)))[t] = ((float4*)fbar)[t];
}

// ---------------- Kernel D: combine partials + Wv + out-proj + LN + norm_aff ----------------
__global__ __launch_bounds__(1024) void finish_kernel(
    const float* __restrict__ slots,
    const float* __restrict__ expsum_part, const float* __restrict__ stat_part,
    const float* __restrict__ aff2_g, const float* __restrict__ fbar_part,
    const float* __restrict__ ipw, const float* __restrict__ ipb,
    const float* __restrict__ wout, const float* __restrict__ bout,
    const float* __restrict__ lnw, const float* __restrict__ lnb,
    float* __restrict__ slots_new, float* __restrict__ norm_aff) {
  __shared__ float fbar[NHEAD][D_];
  __shared__ float srow[D_];
  __shared__ float outv[D_];
  __shared__ float pq[1024];
  __shared__ float redS[4], redQ[4];
  int s = blockIdx.x, t = threadIdx.x, wave = t >> 6, lane = t & 63;

  float st0 = stat_part[s * 4 + 0] + stat_part[s * 4 + 2];
  float st1 = stat_part[s * 4 + 1] + stat_part[s * 4 + 3];
  float mean_a = st0 * (1.0f / NSEL);
  float var_a = st1 * (1.0f / NSEL) - mean_a * mean_a;
  float rstd_a = rsqrtf(var_a + 1e-5f);
  if (t < NSEL) norm_aff[(size_t)t * NSLOT + s] = (aff2_g[s * NSEL + t] - mean_a) * rstd_a;

  if (t < 512) {
    int h = t >> 6;  // fbar layout [8][256]: 64 float4s per head
    float inv = 1.0f / (expsum_part[s * 16 + h] + expsum_part[s * 16 + 8 + h]);
    const float4 a = ((const float4*)(fbar_part + (size_t)s * 4096))[t];
    const float4 c = ((const float4*)(fbar_part + (size_t)s * 4096 + 2048))[t];
    float4 r;
    r.x = (a.x + c.x) * inv; r.y = (a.y + c.y) * inv;
    r.z = (a.z + c.z) * inv; r.w = (a.w + c.w) * inv;
    ((float4*)fbar)[t] = r;
  }
  if (t < 64) ((float4*)srow)[t] = ((const float4*)(slots + (size_t)s * D_))[t];
  __syncthreads();

  {
    int o = t >> 2, part = t & 3, h = o >> 5;
    const float4* wv = (const float4*)(ipw + (size_t)(2 * D_ + o) * D_ + part * 64);
    float a = 0.f;
#pragma unroll
    for (int i = 0; i < 16; i++) {
      float4 w = wv[i];
      int d = part * 64 + i * 4;
      a += fbar[h][d] * w.x + fbar[h][d + 1] * w.y + fbar[h][d + 2] * w.z + fbar[h][d + 3] * w.w;
    }
    pq[t] = a;
  }
  __syncthreads();
  if (t < D_)
    outv[t] = pq[t * 4] + pq[t * 4 + 1] + pq[t * 4 + 2] + pq[t * 4 + 3] + ipb[2 * D_ + t];
  __syncthreads();

  {
    int o = t >> 2, part = t & 3;
    const float4* w4 = (const float4*)(wout + (size_t)o * D_ + part * 64);
    float a = 0.f;
#pragma unroll
    for (int i = 0; i < 16; i++) {
      float4 w = w4[i];
      int d = part * 64 + i * 4;
      a += outv[d] * w.x + outv[d + 1] * w.y + outv[d + 2] * w.z + outv[d + 3] * w.w;
    }
    pq[t] = a;
  }
  __syncthreads();
  float v = 0.f;
  if (t < D_) {
    v = srow[t] + pq[t * 4] + pq[t * 4 + 1] + pq[t * 4 + 2] + pq[t * 4 + 3] + bout[t];
    float ls = v, lq = v * v;
#pragma unroll
    for (int off = 32; off >= 1; off >>= 1) { ls += __shfl_xor(ls, off, 64); lq += __shfl_xor(lq, off, 64); }
    if (lane == 0) { redS[wave] = ls; redQ[wave] = lq; }
  }
  __syncthreads();
  if (t < D_) {
    float tots = redS[0] + redS[1] + redS[2] + redS[3];
    float totq = redQ[0] + redQ[1] + redQ[2] + redQ[3];
    float mean = tots * (1.0f / D_);
    float var = totq * (1.0f / D_) - mean * mean;
    float rstd = rsqrtf(var + 1e-5f);
    slots_new[s * D_ + t] = (v - mean) * rstd * lnw[t] + lnb[t];
  }
}

extern "C" void kernel_launch(void* const* d_in, const int* in_sizes, int n_in,
                              void* d_out, int out_size, void* d_ws, size_t ws_size,
                              hipStream_t stream) {
  const float* slots    = (const float*)d_in[0];
  const float* features = (const float*)d_in[1];
  const float* posenc   = (const float*)d_in[2];
  const float* curio    = (const float*)d_in[3];
  const int*   batch_idx= (const int*)d_in[4];
  const float* ipw      = (const float*)d_in[5];
  const float* ipb      = (const float*)d_in[6];
  const float* wout     = (const float*)d_in[7];
  const float* bout     = (const float*)d_in[8];
  const float* lnw      = (const float*)d_in[9];
  const float* lnb      = (const float*)d_in[10];

  char* ws = (char*)d_ws;
  size_t off = 0;
  int*   feat_sel    = (int*)(ws + off);   off += 256 * 768 * 4;        // 786432
  float* qk_g        = (float*)(ws + off); off += 256 * 8 * 256 * 4;    // 2097152
  float* qbk_g       = (float*)(ws + off); off += 256 * 8 * 4;          // 8192
  float* qksum_g     = (float*)(ws + off); off += 256 * 256 * 4;        // 262144
  unsigned short* qkb16 = (unsigned short*)(ws + off); off += 256 * 4096 * 2; // 2097152
  float* fbar_part   = (float*)(ws + off); off += 256 * 2 * 8 * 256 * 4;// 4194304
  float* expsum_part = (float*)(ws + off); off += 256 * 2 * 8 * 4;      // 16384
  float* stat_part   = (float*)(ws + off); off += 256 * 2 * 2 * 4;      // 4096
  float* aff2_g      = (float*)(ws + off); off += 256 * 768 * 4;        // 786432
  size_t kpf_off = (off + 1023) & ~(size_t)1023;
  unsigned short* kpf = (unsigned short*)(ws + kpf_off);                // 67108864
  bool use_bf16 = (ws_size >= kpf_off + (size_t)HWN * BB * 512 * 2);

  float* out_f = (float*)d_out;  // [0,65536) slots_new, [65536,262144) norm_aff

  if (use_bf16)
    pack_kernel<<<2048, 256, 0, stream>>>(features, posenc, kpf);
  topk_kernel<<<NSLOT, 1024, 0, stream>>>(curio, feat_sel);
  qproj_kernel<<<NSLOT, 256, 0, stream>>>(slots, ipw, ipb, qk_g, qbk_g, qksum_g, qkb16);
  if (use_bf16)
    aff_pv_mfma_kernel<<<NSLOT * 2, 256, 0, stream>>>(kpf, qkb16, batch_idx, feat_sel,
                                                      qbk_g, fbar_part, expsum_part,
                                                      stat_part, aff2_g);
  else
    aff_pv_f32_kernel<<<NSLOT * 2, 512, 0, stream>>>(features, posenc, batch_idx, feat_sel,
                                                     qk_g, qbk_g, qksum_g, fbar_part,
                                                     expsum_part, stat_part, aff2_g);
  finish_kernel<<<NSLOT, 1024, 0, stream>>>(slots, expsum_part, stat_part, aff2_g,
                                            fbar_part, ipw, ipb, wout, bout, lnw, lnb,
                                            out_f, out_f + 65536);
}

// Round 15
// 161.269 us; speedup vs baseline: 1.2048x; 1.0043x over previous
//
#include <hip/hip_runtime.h>
#include <math.h>

#define NSLOT 256
#define HWN   16384
#define D_    256
#define BB    4
#define NSEL  768
#define NPOS  512
#define NHEAD 8

typedef __attribute__((ext_vector_type(8))) short short8v;   // 8 bf16 (4 VGPRs)
typedef __attribute__((ext_vector_type(4))) float float4v;   // MFMA C/D

// global->LDS DMA: size B per lane; LDS dest wave-uniform base; GLOBAL SOURCE PER-LANE.
#define GLD16(g, l)                                                        \
  __builtin_amdgcn_global_load_lds(                                        \
      (__attribute__((address_space(1))) void*)(g),                        \
      (__attribute__((address_space(3))) void*)(l), 16, 0, 0)

#define BFLO(u) __uint_as_float((u) << 16)
#define BFHI(u) __uint_as_float((u) & 0xffff0000u)

__device__ __forceinline__ unsigned short f2bf(float x) {   // RNE bf16
  unsigned u = __float_as_uint(x);
  unsigned r = u + 0x7fffu + ((u >> 16) & 1u);
  return (unsigned short)(r >> 16);
}
__device__ __forceinline__ unsigned int pk2(float a, float b) {
  return (unsigned)f2bf(a) | ((unsigned)f2bf(b) << 16);
}

// ---------------- Kernel P: pack kpf rows (1KB each):
//   [0:512)  = bf16(f+p), 16B-block b stored at phys block b ^ (row&7)  (sigma swizzle)
//   [512:1024) = bf16(f), linear
__global__ __launch_bounds__(256) void pack_kernel(const float* __restrict__ f,
                                                   const float* __restrict__ p,
                                                   unsigned short* __restrict__ kpf) {
  int stride = gridDim.x * 256;
  for (int u = blockIdx.x * 256 + threadIdx.x; u < HWN * BB * 32; u += stride) {
    int row = u >> 5, b = u & 31;
    int c8 = b << 3;
    const float4* f4 = (const float4*)(f + (size_t)row * D_ + c8);
    const float4* p4 = (const float4*)(p + (size_t)row * D_ + c8);
    float4 a0 = f4[0], a1 = f4[1], b0 = p4[0], b1 = p4[1];
    uint4 kp, ff;
    kp.x = pk2(a0.x + b0.x, a0.y + b0.y);
    kp.y = pk2(a0.z + b0.z, a0.w + b0.w);
    kp.z = pk2(a1.x + b1.x, a1.y + b1.y);
    kp.w = pk2(a1.z + b1.z, a1.w + b1.w);
    ff.x = pk2(a0.x, a0.y); ff.y = pk2(a0.z, a0.w);
    ff.z = pk2(a1.x, a1.y); ff.w = pk2(a1.z, a1.w);
    int sig = row & 7;
    *(uint4*)(kpf + (size_t)row * 512 + ((b ^ sig) << 3)) = kp;
    *(uint4*)(kpf + (size_t)row * 512 + 256 + (b << 3)) = ff;
  }
}

// ---------------- Kernel A: per-slot top-768 stable select (1024 thr) ----------------
__global__ __launch_bounds__(1024) void topk_kernel(const float* __restrict__ curio,
                                                    int* __restrict__ feat_sel) {
  __shared__ unsigned int hist[4096];
  __shared__ unsigned int wsum[16];
  __shared__ unsigned long long skey[2048];
  __shared__ int sBstar;
  __shared__ unsigned int sCount;
  int s = blockIdx.x;
  int t = threadIdx.x;
  int wave = t >> 6, lane = t & 63;
  const float* row = curio + (size_t)s * HWN;

  for (int i = t; i < 4096; i += 1024) hist[i] = 0;
  if (t == 0) sCount = 0;
  __syncthreads();
  for (int j = t; j < HWN; j += 1024) {
    unsigned int bits = __float_as_uint(row[j]);   // values in [0,1): bits monotone
    atomicAdd(&hist[bits >> 18], 1u);
  }
  __syncthreads();
  unsigned int cs = hist[t * 4] + hist[t * 4 + 1] + hist[t * 4 + 2] + hist[t * 4 + 3];
  unsigned int v = cs;
#pragma unroll
  for (int off = 1; off < 64; off <<= 1) {
    unsigned int u = __shfl_down(v, off, 64);
    if (lane + off < 64) v += u;       // suffix over lanes >= lane (this wave)
  }
  if (lane == 0) wsum[wave] = v;
  __syncthreads();
  unsigned int above = 0;
  for (int w2 = wave + 1; w2 < 16; w2++) above += wsum[w2];
  unsigned int sufAfter = above + (v - cs);
  if (sufAfter < NSEL && sufAfter + cs >= NSEL) {
    unsigned int local = sufAfter;
    for (int b = t * 4 + 3; b >= t * 4; b--) {
      unsigned int c = hist[b];
      if (local + c >= NSEL) { sBstar = b; break; }
      local += c;
    }
  }
  __syncthreads();
  int bstar = sBstar;
  for (int j = t; j < HWN; j += 1024) {
    unsigned int bits = __float_as_uint(row[j]);
    if ((int)(bits >> 18) >= bstar) {
      unsigned int pos = atomicAdd(&sCount, 1u);
      if (pos < 2048)
        skey[pos] = ((unsigned long long)bits << 14) | (unsigned long long)(16383 - j);
    }
  }
  __syncthreads();
  unsigned int M = sCount;
  int SZ = (M <= 1024) ? 1024 : 2048;
  for (int i = t; i < SZ; i += 1024) if (i >= (int)M) skey[i] = 0ull;
  for (int k = 2; k <= SZ; k <<= 1) {
    for (int j2 = k >> 1; j2 > 0; j2 >>= 1) {
      __syncthreads();
      for (int i = t; i < SZ; i += 1024) {
        int l = i ^ j2;
        if (l > i) {
          unsigned long long a = skey[i], b = skey[l];
          bool dir = ((i & k) == 0);
          if ((a < b) == dir) { skey[i] = b; skey[l] = a; }
        }
      }
    }
  }
  __syncthreads();
  for (int r = t; r < NSEL; r += 1024)
    feat_sel[s * NSEL + r] = 16383 - (int)(skey[r] & 16383ull);
}

// ---------------- Kernel B: q proj + qk + qksum + qkb16 (MFMA B-frags) ----------------
__global__ __launch_bounds__(256) void qproj_kernel(const float* __restrict__ slots,
                                                    const float* __restrict__ ipw,
                                                    const float* __restrict__ ipb,
                                                    float* __restrict__ qk_g,
                                                    float* __restrict__ qbk_g,
                                                    float* __restrict__ qksum_g,
                                                    unsigned short* __restrict__ qkb16) {
  __shared__ float srow[D_];
  __shared__ float qrow[D_];
  __shared__ float qkl[NHEAD][D_];
  __shared__ float qsl[D_];
  int s = blockIdx.x, t = threadIdx.x;
  srow[t] = slots[s * D_ + t];
  __syncthreads();
  {
    const float* wq = ipw + (size_t)t * D_;
    float acc = ipb[t];
    for (int d = 0; d < D_; d++) acc += srow[d] * wq[d];
    qrow[t] = acc * 0.17677669529663689f;  // 1/sqrt(32)
  }
  __syncthreads();
  float qsum = 0.f;
  for (int h = 0; h < NHEAD; h++) {
    const float* wkbase = ipw + (size_t)(D_ + h * 32) * D_ + t;
    float a = 0.f;
    for (int e = 0; e < 32; e++) a += qrow[h * 32 + e] * wkbase[(size_t)e * D_];
    qk_g[((size_t)s * NHEAD + h) * D_ + t] = a;
    qkl[h][t] = a;
    qsum += a;
  }
  qksum_g[s * D_ + t] = qsum;
  qsl[t] = qsum;
  if (t < NHEAD) {
    float a = 0.f;
    for (int e = 0; e < 32; e++) a += qrow[t * 32 + e] * ipb[D_ + t * 32 + e];
    qbk_g[s * NHEAD + t] = a;
  }
  __syncthreads();
  // qkb16[s][e], e = ((kc*64 + l)*8 + j): B-frag order. col=l&15; k=kc*32+((l>>4)&3)*8+j.
  // cols 0-7 = heads, col 8 = qksum, cols 9-15 = 0.
  for (int i = 0; i < 16; i++) {
    int e = t * 16 + i;
    int kc = e >> 9, l = (e >> 3) & 63, j = e & 7;
    int cc = l & 15, k = kc * 32 + ((l >> 4) & 3) * 8 + j;
    float v = (cc < NHEAD) ? qkl[cc][k] : ((cc == NHEAD) ? qsl[k] : 0.f);
    qkb16[(size_t)s * 4096 + e] = f2bf(v);
  }
}

// ---------------- Kernel C (MFMA): aff via matrix cores + scalar PV ----------------
// grid = (slot, half), 256 thr (4 waves). Wave w: 6 tiles of 16 rows:
// tiles 0-3 pos rows [w*64 .. w*64+64), tiles 4-5 neg rows 256+[w*32 .. +32).
// DMA: 8x GLD16 per tile (ROW-PAIRED: lanes 0-31 row A kp, 32-63 row B kp) —
// R14 lesson: gather rate scales with DMA instruction count; 32 GLD4 -> 8 GLD16.
// kp is sigma-swizzled in kpf (block b at b^(row&7)); A-frag reads apply sigma.
__global__ __launch_bounds__(256, 3) void aff_pv_mfma_kernel(
    const unsigned short* __restrict__ kpf,
    const unsigned short* __restrict__ qkb16,
    const int* __restrict__ batch_idx, const int* __restrict__ feat_sel,
    const float* __restrict__ qbk_g,
    float* __restrict__ fbar_part,    // [256][2][8][256]
    float* __restrict__ expsum_part,  // [256][2][8]
    float* __restrict__ stat_part,    // [256][2][2]
    float* __restrict__ aff2_g) {     // [256][768]
  __shared__ unsigned short kplds[4][4096];     // 32 KB: per-wave 16 rows x 512B (sigma layout)
  __shared__ unsigned short qkb[4096];          // 8 KB
  __shared__ float wlds[4][16][17];             // 4.3 KB
  __shared__ float fbar[NHEAD][D_];             // 8 KB
  __shared__ float a2buf[384];
  __shared__ int   sfsel[384];
  __shared__ float esums[4][NHEAD];
  __shared__ float sstat[4][2];
  __shared__ float qbkmean_s;

  int b = blockIdx.x, s = b >> 1, half = b & 1;
  int t = threadIdx.x, w = t >> 6, lane = t & 63;
  int bi = batch_idx[s];
  int col = lane & 15, quad = lane >> 4;

  {
    const uint4* src = (const uint4*)(qkb16 + (size_t)s * 4096);
    ((uint4*)qkb)[t] = src[t];
    ((uint4*)qkb)[t + 256] = src[t + 256];
  }
  for (int i = t; i < 384; i += 256) sfsel[i] = feat_sel[s * NSEL + half + 2 * i];
  for (int i = t; i < NHEAD * D_; i += 256) ((float*)fbar)[i] = 0.f;
  if (t == 0) {
    float m = 0.f;
    for (int h = 0; h < NHEAD; h++) m += qbk_g[s * NHEAD + h];
    qbkmean_s = m * 0.125f;
  }
  __syncthreads();

  unsigned short* kslot = &kplds[w][0];
  float acc[NHEAD][4];
#pragma unroll
  for (int h = 0; h < NHEAD; h++)
#pragma unroll
    for (int c = 0; c < 4; c++) acc[h][c] = 0.f;
  float esum_acc = 0.f;  // valid on lanes with col<8 (head=col)

  // 8 paired GLD16: lanes 0-31 <- row 2p kp-half, lanes 32-63 <- row 2p+1 kp-half.
  auto ISSUE_KP = [&](int L) {
#pragma unroll
    for (int p = 0; p < 8; p++) {
      int r0 = sfsel[L + 2 * p], r1 = sfsel[L + 2 * p + 1];
      unsigned ridx = (unsigned)((lane < 32 ? r0 : r1) * BB + bi);
      const unsigned short* src = kpf + (size_t)ridx * 512 + (lane & 31) * 8;
      GLD16(src, kslot + p * 512);
    }
  };

  ISSUE_KP(w * 64);  // prologue: tile 0
#pragma unroll 1
  for (int i = 0; i < 6; i++) {
    int L = (i < 4) ? (w * 64 + i * 16) : (256 + w * 32 + (i - 4) * 16);
    asm volatile("s_waitcnt vmcnt(0)" ::: "memory");  // tile i's 8 DMAs landed
    bool pos = (i < 4);
    uint2 fu[16];
    if (pos) {
#pragma unroll
      for (int r = 0; r < 16; r++)
        fu[r] = *(const uint2*)(kpf + (size_t)((unsigned)sfsel[L + r] * BB + bi) * 512 +
                                256 + lane * 4);
    }
    // A-frags: row col, k-block (kc*4+quad) xor sigma(row)
    unsigned sig = ((unsigned)sfsel[L + col] * BB + bi) & 7u;
    short8v afr[8];
#pragma unroll
    for (int kc = 0; kc < 8; kc++) {
      unsigned blk = ((unsigned)(kc * 4 + quad)) ^ sig;
      afr[kc] = *(const short8v*)(kslot + col * 256 + blk * 8);
    }
    asm volatile("s_waitcnt lgkmcnt(0)" ::: "memory");  // A reads done before slot reuse
    __builtin_amdgcn_sched_barrier(0);
    if (i < 5) {
      int Ln = (i < 3) ? (w * 64 + (i + 1) * 16) : (256 + w * 32 + (i - 3) * 16);
      ISSUE_KP(Ln);
    }
    float4v c = {0.f, 0.f, 0.f, 0.f};
#pragma unroll
    for (int kc = 0; kc < 8; kc++) {
      short8v bfr = *(const short8v*)&qkb[(kc * 64 + lane) * 8];
      c = __builtin_amdgcn_mfma_f32_16x16x32_bf16(afr[kc], bfr, c, 0, 0, 0);
    }
    // C: row n = quad*4+j (local row L+n), col: 0-7 heads, 8 = qksum-dot
    if (pos) {
      if (col < NHEAD) {
        float e0 = __expf(c[0]), e1 = __expf(c[1]), e2 = __expf(c[2]), e3 = __expf(c[3]);
        esum_acc += e0 + e1 + e2 + e3;
        wlds[w][quad * 4 + 0][col] = e0;
        wlds[w][quad * 4 + 1][col] = e1;
        wlds[w][quad * 4 + 2][col] = e2;
        wlds[w][quad * 4 + 3][col] = e3;
      } else if (col == NHEAD) {
        float qm = qbkmean_s;
#pragma unroll
        for (int j = 0; j < 4; j++) a2buf[L + quad * 4 + j] = c[j] * 0.125f + qm;
      }
      asm volatile("s_waitcnt lgkmcnt(0)" ::: "memory");  // wlds writes visible in-wave
      __builtin_amdgcn_sched_barrier(0);
#pragma unroll
      for (int r = 0; r < 16; r++) {
        const float4 w0 = *(const float4*)&wlds[w][r][0];
        const float4 w1 = *(const float4*)&wlds[w][r][4];
        float f0 = BFLO(fu[r].x), f1 = BFHI(fu[r].x), f2 = BFLO(fu[r].y), f3 = BFHI(fu[r].y);
        acc[0][0] += w0.x * f0; acc[0][1] += w0.x * f1; acc[0][2] += w0.x * f2; acc[0][3] += w0.x * f3;
        acc[1][0] += w0.y * f0; acc[1][1] += w0.y * f1; acc[1][2] += w0.y * f2; acc[1][3] += w0.y * f3;
        acc[2][0] += w0.z * f0; acc[2][1] += w0.z * f1; acc[2][2] += w0.z * f2; acc[2][3] += w0.z * f3;
        acc[3][0] += w0.w * f0; acc[3][1] += w0.w * f1; acc[3][2] += w0.w * f2; acc[3][3] += w0.w * f3;
        acc[4][0] += w1.x * f0; acc[4][1] += w1.x * f1; acc[4][2] += w1.x * f2; acc[4][3] += w1.x * f3;
        acc[5][0] += w1.y * f0; acc[5][1] += w1.y * f1; acc[5][2] += w1.y * f2; acc[5][3] += w1.y * f3;
        acc[6][0] += w1.z * f0; acc[6][1] += w1.z * f1; acc[6][2] += w1.z * f2; acc[6][3] += w1.z * f3;
        acc[7][0] += w1.w * f0; acc[7][1] += w1.w * f1; acc[7][2] += w1.w * f2; acc[7][3] += w1.w * f3;
      }
    } else {
      if (col == NHEAD) {
        float qm = qbkmean_s;
#pragma unroll
        for (int j = 0; j < 4; j++) a2buf[L + quad * 4 + j] = c[j] * 0.125f + qm;
      }
    }
  }

  // esum: combine quads (lanes h, h+16, h+32, h+48 all have col==h for h<8)
  esum_acc += __shfl_xor(esum_acc, 16, 64);
  esum_acc += __shfl_xor(esum_acc, 32, 64);
  if (lane < NHEAD) esums[w][lane] = esum_acc;
#pragma unroll
  for (int h = 0; h < NHEAD; h++) {
    atomicAdd(&fbar[h][lane * 4 + 0], acc[h][0]);
    atomicAdd(&fbar[h][lane * 4 + 1], acc[h][1]);
    atomicAdd(&fbar[h][lane * 4 + 2], acc[h][2]);
    atomicAdd(&fbar[h][lane * 4 + 3], acc[h][3]);
  }
  __syncthreads();

  {
    float v1 = a2buf[t];
    float v2 = (t < 128) ? a2buf[256 + t] : 0.f;
    float ls = v1 + v2, lq = v1 * v1 + v2 * v2;
#pragma unroll
    for (int off = 32; off >= 1; off >>= 1) { ls += __shfl_xor(ls, off, 64); lq += __shfl_xor(lq, off, 64); }
    if (lane == 0) { sstat[w][0] = ls; sstat[w][1] = lq; }
  }
  __syncthreads();
  if (t < NHEAD) {
    expsum_part[b * NHEAD + t] = esums[0][t] + esums[1][t] + esums[2][t] + esums[3][t];
  } else if (t == NHEAD) {
    stat_part[b * 2 + 0] = sstat[0][0] + sstat[1][0] + sstat[2][0] + sstat[3][0];
    stat_part[b * 2 + 1] = sstat[0][1] + sstat[1][1] + sstat[2][1] + sstat[3][1];
  }
  aff2_g[s * NSEL + half + 2 * t] = a2buf[t];
  if (t < 128) aff2_g[s * NSEL + half + 2 * (256 + t)] = a2buf[256 + t];
  ((float4*)(fbar_part + (size_t)b * 2048))[t] = ((float4*)fbar)[t];
  ((float4*)(fbar_part + (size_t)b * 2048))[t + 256] = ((float4*)fbar)[t + 256];
}

// ---------------- Kernel D: combine partials + Wv + out-proj + LN + norm_aff ----------------
__global__ __launch_bounds__(1024) void finish_kernel(
    const float* __restrict__ slots,
    const float* __restrict__ expsum_part, const float* __restrict__ stat_part,
    const float* __restrict__ aff2_g, const float* __restrict__ fbar_part,
    const float* __restrict__ ipw, const float* __restrict__ ipb,
    const float* __restrict__ wout, const float* __restrict__ bout,
    const float* __restrict__ lnw, const float* __restrict__ lnb,
    float* __restrict__ slots_new, float* __restrict__ norm_aff) {
  __shared__ float fbar[NHEAD][D_];
  __shared__ float srow[D_];
  __shared__ float outv[D_];
  __shared__ float pq[1024];
  __shared__ float redS[4], redQ[4];
  int s = blockIdx.x, t = threadIdx.x, wave = t >> 6, lane = t & 63;

  float st0 = stat_part[s * 4 + 0] + stat_part[s * 4 + 2];
  float st1 = stat_part[s * 4 + 1] + stat_part[s * 4 + 3];
  float mean_a = st0 * (1.0f / NSEL);
  float var_a = st1 * (1.0f / NSEL) - mean_a * mean_a;
  float rstd_a = rsqrtf(var_a + 1e-5f);
  if (t < NSEL) norm_aff[(size_t)t * NSLOT + s] = (aff2_g[s * NSEL + t] - mean_a) * rstd_a;

  if (t < 512) {
    int h = t >> 6;  // fbar layout [8][256]: 64 float4s per head
    float inv = 1.0f / (expsum_part[s * 16 + h] + expsum_part[s * 16 + 8 + h]);
    const float4 a = ((const float4*)(fbar_part + (size_t)s * 4096))[t];
    const float4 c = ((const float4*)(fbar_part + (size_t)s * 4096 + 2048))[t];
    float4 r;
    r.x = (a.x + c.x) * inv; r.y = (a.y + c.y) * inv;
    r.z = (a.z + c.z) * inv; r.w = (a.w + c.w) * inv;
    ((float4*)fbar)[t] = r;
  }
  if (t < 64) ((float4*)srow)[t] = ((const float4*)(slots + (size_t)s * D_))[t];
  __syncthreads();

  {
    int o = t >> 2, part = t & 3, h = o >> 5;
    const float4* wv = (const float4*)(ipw + (size_t)(2 * D_ + o) * D_ + part * 64);
    float a = 0.f;
#pragma unroll
    for (int i = 0; i < 16; i++) {
      float4 w = wv[i];
      int d = part * 64 + i * 4;
      a += fbar[h][d] * w.x + fbar[h][d + 1] * w.y + fbar[h][d + 2] * w.z + fbar[h][d + 3] * w.w;
    }
    pq[t] = a;
  }
  __syncthreads();
  if (t < D_)
    outv[t] = pq[t * 4] + pq[t * 4 + 1] + pq[t * 4 + 2] + pq[t * 4 + 3] + ipb[2 * D_ + t];
  __syncthreads();

  {
    int o = t >> 2, part = t & 3;
    const float4* w4 = (const float4*)(wout + (size_t)o * D_ + part * 64);
    float a = 0.f;
#pragma unroll
    for (int i = 0; i < 16; i++) {
      float4 w = w4[i];
      int d = part * 64 + i * 4;
      a += outv[d] * w.x + outv[d + 1] * w.y + outv[d + 2] * w.z + outv[d + 3] * w.w;
    }
    pq[t] = a;
  }
  __syncthreads();
  float v = 0.f;
  if (t < D_) {
    v = srow[t] + pq[t * 4] + pq[t * 4 + 1] + pq[t * 4 + 2] + pq[t * 4 + 3] + bout[t];
    float ls = v, lq = v * v;
#pragma unroll
    for (int off = 32; off >= 1; off >>= 1) { ls += __shfl_xor(ls, off, 64); lq += __shfl_xor(lq, off, 64); }
    if (lane == 0) { redS[wave] = ls; redQ[wave] = lq; }
  }
  __syncthreads();
  if (t < D_) {
    float tots = redS[0] + redS[1] + redS[2] + redS[3];
    float totq = redQ[0] + redQ[1] + redQ[2] + redQ[3];
    float mean = tots * (1.0f / D_);
    float var = totq * (1.0f / D_) - mean * mean;
    float rstd = rsqrtf(var + 1e-5f);
    slots_new[s * D_ + t] = (v - mean) * rstd * lnw[t] + lnb[t];
  }
}

extern "C" void kernel_launch(void* const* d_in, const int* in_sizes, int n_in,
                              void* d_out, int out_size, void* d_ws, size_t ws_size,
                              hipStream_t stream) {
  const float* slots    = (const float*)d_in[0];
  const float* features = (const float*)d_in[1];
  const float* posenc   = (const float*)d_in[2];
  const float* curio    = (const float*)d_in[3];
  const int*   batch_idx= (const int*)d_in[4];
  const float* ipw      = (const float*)d_in[5];
  const float* ipb      = (const float*)d_in[6];
  const float* wout     = (const float*)d_in[7];
  const float* bout     = (const float*)d_in[8];
  const float* lnw      = (const float*)d_in[9];
  const float* lnb      = (const float*)d_in[10];

  char* ws = (char*)d_ws;
  size_t off = 0;
  int*   feat_sel    = (int*)(ws + off);   off += 256 * 768 * 4;        // 786432
  float* qk_g        = (float*)(ws + off); off += 256 * 8 * 256 * 4;    // 2097152
  float* qbk_g       = (float*)(ws + off); off += 256 * 8 * 4;          // 8192
  float* qksum_g     = (float*)(ws + off); off += 256 * 256 * 4;        // 262144
  unsigned short* qkb16 = (unsigned short*)(ws + off); off += 256 * 4096 * 2; // 2097152
  float* fbar_part   = (float*)(ws + off); off += 256 * 2 * 8 * 256 * 4;// 4194304
  float* expsum_part = (float*)(ws + off); off += 256 * 2 * 8 * 4;      // 16384
  float* stat_part   = (float*)(ws + off); off += 256 * 2 * 2 * 4;      // 4096
  float* aff2_g      = (float*)(ws + off); off += 256 * 768 * 4;        // 786432
  size_t kpf_off = (off + 1023) & ~(size_t)1023;
  unsigned short* kpf = (unsigned short*)(ws + kpf_off);                // 67108864

  float* out_f = (float*)d_out;  // [0,65536) slots_new, [65536,262144) norm_aff

  pack_kernel<<<2048, 256, 0, stream>>>(features, posenc, kpf);
  topk_kernel<<<NSLOT, 1024, 0, stream>>>(curio, feat_sel);
  qproj_kernel<<<NSLOT, 256, 0, stream>>>(slots, ipw, ipb, qk_g, qbk_g, qksum_g, qkb16);
  aff_pv_mfma_kernel<<<NSLOT * 2, 256, 0, stream>>>(kpf, qkb16, batch_idx, feat_sel,
                                                    qbk_g, fbar_part, expsum_part,
                                                    stat_part, aff2_g);
  finish_kernel<<<NSLOT, 1024, 0, stream>>>(slots, expsum_part, stat_part, aff2_g,
                                            fbar_part, ipw, ipb, wout, bout, lnw, lnb,
                                            out_f, out_f + 65536);
}

// Round 16
// 144.135 us; speedup vs baseline: 1.3480x; 1.1189x over previous
//
#include <hip/hip_runtime.h>
#include <math.h>

#define NSLOT 256
#define HWN   16384
#define D_    256
#define BB    4
#define NSEL  768
#define NPOS  512
#define NHEAD 8

typedef __attribute__((ext_vector_type(8))) short short8v;   // 8 bf16 (4 VGPRs)
typedef __attribute__((ext_vector_type(4))) float float4v;   // MFMA C/D

// global->LDS DMA: 16B per lane; LDS dest wave-uniform base; GLOBAL SOURCE PER-LANE.
#define GLD16(g, l)                                                        \
  __builtin_amdgcn_global_load_lds(                                        \
      (__attribute__((address_space(1))) void*)(g),                        \
      (__attribute__((address_space(3))) void*)(l), 16, 0, 0)

#define BFLO(u) __uint_as_float((u) << 16)
#define BFHI(u) __uint_as_float((u) & 0xffff0000u)

__device__ __forceinline__ unsigned short f2bf(float x) {   // RNE bf16
  unsigned u = __float_as_uint(x);
  unsigned r = u + 0x7fffu + ((u >> 16) & 1u);
  return (unsigned short)(r >> 16);
}
__device__ __forceinline__ unsigned int pk2(float a, float b) {
  return (unsigned)f2bf(a) | ((unsigned)f2bf(b) << 16);
}

// ---------------- Kernel PREP: fused topk (blocks 0-255) | qproj x4 slots (256-319)
//                  | pack (320-831, grid-strided). Independent inputs -> run concurrently.
union PrepSmem {
  struct {
    unsigned int hist[4096];
    unsigned int wsum[16];
    unsigned long long skey[2048];
    int sBstar;
    unsigned int sCount;
  } tk;                                   // ~32.8 KB
  struct {
    float srow[4][D_];
    float qrow[4][D_];
    float qkl[4][NHEAD][D_];
    float qsl[4][D_];
  } qp;                                   // 44 KB
};

__global__ __launch_bounds__(1024) void prep_kernel(
    const float* __restrict__ curio, int* __restrict__ feat_sel,
    const float* __restrict__ slots, const float* __restrict__ ipw,
    const float* __restrict__ ipb, float* __restrict__ qbk_g,
    unsigned short* __restrict__ qkb16,
    const float* __restrict__ fsrc, const float* __restrict__ psrc,
    unsigned short* __restrict__ kpf) {
  __shared__ PrepSmem sm;
  int B = blockIdx.x;
  int t = threadIdx.x;

  if (B < 256) {
    // ---------------- topk: per-slot top-768 stable select ----------------
    int s = B;
    int wave = t >> 6, lane = t & 63;
    const float* row = curio + (size_t)s * HWN;

    for (int i = t; i < 4096; i += 1024) sm.tk.hist[i] = 0;
    if (t == 0) sm.tk.sCount = 0;
    __syncthreads();
    for (int j = t; j < HWN; j += 1024) {
      unsigned int bits = __float_as_uint(row[j]);   // values in [0,1): bits monotone
      atomicAdd(&sm.tk.hist[bits >> 18], 1u);
    }
    __syncthreads();
    unsigned int cs = sm.tk.hist[t * 4] + sm.tk.hist[t * 4 + 1] +
                      sm.tk.hist[t * 4 + 2] + sm.tk.hist[t * 4 + 3];
    unsigned int v = cs;
#pragma unroll
    for (int off = 1; off < 64; off <<= 1) {
      unsigned int u = __shfl_down(v, off, 64);
      if (lane + off < 64) v += u;       // suffix over lanes >= lane (this wave)
    }
    if (lane == 0) sm.tk.wsum[wave] = v;
    __syncthreads();
    unsigned int above = 0;
    for (int w2 = wave + 1; w2 < 16; w2++) above += sm.tk.wsum[w2];
    unsigned int sufAfter = above + (v - cs);
    if (sufAfter < NSEL && sufAfter + cs >= NSEL) {
      unsigned int local = sufAfter;
      for (int b2 = t * 4 + 3; b2 >= t * 4; b2--) {
        unsigned int c = sm.tk.hist[b2];
        if (local + c >= NSEL) { sm.tk.sBstar = b2; break; }
        local += c;
      }
    }
    __syncthreads();
    int bstar = sm.tk.sBstar;
    for (int j = t; j < HWN; j += 1024) {
      unsigned int bits = __float_as_uint(row[j]);
      if ((int)(bits >> 18) >= bstar) {
        unsigned int pos = atomicAdd(&sm.tk.sCount, 1u);
        if (pos < 2048)
          sm.tk.skey[pos] = ((unsigned long long)bits << 14) |
                            (unsigned long long)(16383 - j);
      }
    }
    __syncthreads();
    unsigned int M = sm.tk.sCount;
    int SZ = (M <= 1024) ? 1024 : 2048;
    for (int i = t; i < SZ; i += 1024) if (i >= (int)M) sm.tk.skey[i] = 0ull;
    for (int k = 2; k <= SZ; k <<= 1) {
      for (int j2 = k >> 1; j2 > 0; j2 >>= 1) {
        __syncthreads();
        for (int i = t; i < SZ; i += 1024) {
          int l = i ^ j2;
          if (l > i) {
            unsigned long long a = sm.tk.skey[i], b2 = sm.tk.skey[l];
            bool dir = ((i & k) == 0);
            if ((a < b2) == dir) { sm.tk.skey[i] = b2; sm.tk.skey[l] = a; }
          }
        }
      }
    }
    __syncthreads();
    for (int r = t; r < NSEL; r += 1024)
      feat_sel[s * NSEL + r] = 16383 - (int)(sm.tk.skey[r] & 16383ull);
  } else if (B < 320) {
    // ---------------- qproj: 4 slots per block (sub = t>>8) ----------------
    int sub = t >> 8, tt = t & 255;
    int s = (B - 256) * 4 + sub;
    float* srow = sm.qp.srow[sub];
    float* qrow = sm.qp.qrow[sub];
    float* qsl = sm.qp.qsl[sub];
    srow[tt] = slots[s * D_ + tt];
    __syncthreads();
    {
      const float* wq = ipw + (size_t)tt * D_;
      float acc = ipb[tt];
      for (int d = 0; d < D_; d++) acc += srow[d] * wq[d];
      qrow[tt] = acc * 0.17677669529663689f;  // 1/sqrt(32)
    }
    __syncthreads();
    float qsum = 0.f;
    for (int h = 0; h < NHEAD; h++) {
      const float* wkbase = ipw + (size_t)(D_ + h * 32) * D_ + tt;
      float a = 0.f;
      for (int e = 0; e < 32; e++) a += qrow[h * 32 + e] * wkbase[(size_t)e * D_];
      sm.qp.qkl[sub][h][tt] = a;
      qsum += a;
    }
    qsl[tt] = qsum;
    if (tt < NHEAD) {
      float a = 0.f;
      for (int e = 0; e < 32; e++) a += qrow[tt * 32 + e] * ipb[D_ + tt * 32 + e];
      qbk_g[s * NHEAD + tt] = a;
    }
    __syncthreads();
    // qkb16[s][e], e = ((kc*64+l)*8+j): B-frag order. col=l&15; k=kc*32+((l>>4)&3)*8+j.
    for (int i = 0; i < 16; i++) {
      int e = tt * 16 + i;
      int kc = e >> 9, l = (e >> 3) & 63, j = e & 7;
      int cc = l & 15, k = kc * 32 + ((l >> 4) & 3) * 8 + j;
      float v = (cc < NHEAD) ? sm.qp.qkl[sub][cc][k] : ((cc == NHEAD) ? qsl[k] : 0.f);
      qkb16[(size_t)s * 4096 + e] = f2bf(v);
    }
  } else {
    // ---------------- pack: kpf rows (1KB): [0:512) sigma-swizzled bf16(f+p),
    //                  [512:1024) linear bf16(f) ----------------
    int stride = 512 * 1024;
    for (int u = (B - 320) * 1024 + t; u < HWN * BB * 32; u += stride) {
      int row = u >> 5, b2 = u & 31;
      int c8 = b2 << 3;
      const float4* f4 = (const float4*)(fsrc + (size_t)row * D_ + c8);
      const float4* p4 = (const float4*)(psrc + (size_t)row * D_ + c8);
      float4 a0 = f4[0], a1 = f4[1], b0 = p4[0], b1 = p4[1];
      uint4 kp, ff;
      kp.x = pk2(a0.x + b0.x, a0.y + b0.y);
      kp.y = pk2(a0.z + b0.z, a0.w + b0.w);
      kp.z = pk2(a1.x + b1.x, a1.y + b1.y);
      kp.w = pk2(a1.z + b1.z, a1.w + b1.w);
      ff.x = pk2(a0.x, a0.y); ff.y = pk2(a0.z, a0.w);
      ff.z = pk2(a1.x, a1.y); ff.w = pk2(a1.z, a1.w);
      int sig = row & 7;
      *(uint4*)(kpf + (size_t)row * 512 + ((b2 ^ sig) << 3)) = kp;
      *(uint4*)(kpf + (size_t)row * 512 + 256 + (c8)) = ff;
    }
  }
}

// ---------------- Kernel C (MFMA): aff via matrix cores + scalar PV (R15, passing) ----------------
__global__ __launch_bounds__(256, 3) void aff_pv_mfma_kernel(
    const unsigned short* __restrict__ kpf,
    const unsigned short* __restrict__ qkb16,
    const int* __restrict__ batch_idx, const int* __restrict__ feat_sel,
    const float* __restrict__ qbk_g,
    float* __restrict__ fbar_part,    // [256][2][8][256]
    float* __restrict__ expsum_part,  // [256][2][8]
    float* __restrict__ stat_part,    // [256][2][2]
    float* __restrict__ aff2_g) {     // [256][768]
  __shared__ unsigned short kplds[4][4096];     // 32 KB: per-wave 16 rows x 512B (sigma layout)
  __shared__ unsigned short qkb[4096];          // 8 KB
  __shared__ float wlds[4][16][17];             // 4.3 KB
  __shared__ float fbar[NHEAD][D_];             // 8 KB
  __shared__ float a2buf[384];
  __shared__ int   sfsel[384];
  __shared__ float esums[4][NHEAD];
  __shared__ float sstat[4][2];
  __shared__ float qbkmean_s;

  int b = blockIdx.x, s = b >> 1, half = b & 1;
  int t = threadIdx.x, w = t >> 6, lane = t & 63;
  int bi = batch_idx[s];
  int col = lane & 15, quad = lane >> 4;

  {
    const uint4* src = (const uint4*)(qkb16 + (size_t)s * 4096);
    ((uint4*)qkb)[t] = src[t];
    ((uint4*)qkb)[t + 256] = src[t + 256];
  }
  for (int i = t; i < 384; i += 256) sfsel[i] = feat_sel[s * NSEL + half + 2 * i];
  for (int i = t; i < NHEAD * D_; i += 256) ((float*)fbar)[i] = 0.f;
  if (t == 0) {
    float m = 0.f;
    for (int h = 0; h < NHEAD; h++) m += qbk_g[s * NHEAD + h];
    qbkmean_s = m * 0.125f;
  }
  __syncthreads();

  unsigned short* kslot = &kplds[w][0];
  float acc[NHEAD][4];
#pragma unroll
  for (int h = 0; h < NHEAD; h++)
#pragma unroll
    for (int c = 0; c < 4; c++) acc[h][c] = 0.f;
  float esum_acc = 0.f;  // valid on lanes with col<8 (head=col)

  // 8 paired GLD16: lanes 0-31 <- row 2p kp-half, lanes 32-63 <- row 2p+1 kp-half.
  auto ISSUE_KP = [&](int L) {
#pragma unroll
    for (int p = 0; p < 8; p++) {
      int r0 = sfsel[L + 2 * p], r1 = sfsel[L + 2 * p + 1];
      unsigned ridx = (unsigned)((lane < 32 ? r0 : r1) * BB + bi);
      const unsigned short* src = kpf + (size_t)ridx * 512 + (lane & 31) * 8;
      GLD16(src, kslot + p * 512);
    }
  };

  ISSUE_KP(w * 64);  // prologue: tile 0
#pragma unroll 1
  for (int i = 0; i < 6; i++) {
    int L = (i < 4) ? (w * 64 + i * 16) : (256 + w * 32 + (i - 4) * 16);
    asm volatile("s_waitcnt vmcnt(0)" ::: "memory");  // tile i's 8 DMAs landed
    bool pos = (i < 4);
    uint2 fu[16];
    if (pos) {
#pragma unroll
      for (int r = 0; r < 16; r++)
        fu[r] = *(const uint2*)(kpf + (size_t)((unsigned)sfsel[L + r] * BB + bi) * 512 +
                                256 + lane * 4);
    }
    // A-frags: row col, k-block (kc*4+quad) xor sigma(row)
    unsigned sig = ((unsigned)sfsel[L + col] * BB + bi) & 7u;
    short8v afr[8];
#pragma unroll
    for (int kc = 0; kc < 8; kc++) {
      unsigned blk = ((unsigned)(kc * 4 + quad)) ^ sig;
      afr[kc] = *(const short8v*)(kslot + col * 256 + blk * 8);
    }
    asm volatile("s_waitcnt lgkmcnt(0)" ::: "memory");  // A reads done before slot reuse
    __builtin_amdgcn_sched_barrier(0);
    if (i < 5) {
      int Ln = (i < 3) ? (w * 64 + (i + 1) * 16) : (256 + w * 32 + (i - 3) * 16);
      ISSUE_KP(Ln);
    }
    float4v c = {0.f, 0.f, 0.f, 0.f};
#pragma unroll
    for (int kc = 0; kc < 8; kc++) {
      short8v bfr = *(const short8v*)&qkb[(kc * 64 + lane) * 8];
      c = __builtin_amdgcn_mfma_f32_16x16x32_bf16(afr[kc], bfr, c, 0, 0, 0);
    }
    // C: row n = quad*4+j (local row L+n), col: 0-7 heads, 8 = qksum-dot
    if (pos) {
      if (col < NHEAD) {
        float e0 = __expf(c[0]), e1 = __expf(c[1]), e2 = __expf(c[2]), e3 = __expf(c[3]);
        esum_acc += e0 + e1 + e2 + e3;
        wlds[w][quad * 4 + 0][col] = e0;
        wlds[w][quad * 4 + 1][col] = e1;
        wlds[w][quad * 4 + 2][col] = e2;
        wlds[w][quad * 4 + 3][col] = e3;
      } else if (col == NHEAD) {
        float qm = qbkmean_s;
#pragma unroll
        for (int j = 0; j < 4; j++) a2buf[L + quad * 4 + j] = c[j] * 0.125f + qm;
      }
      asm volatile("s_waitcnt lgkmcnt(0)" ::: "memory");  // wlds writes visible in-wave
      __builtin_amdgcn_sched_barrier(0);
#pragma unroll
      for (int r = 0; r < 16; r++) {
        const float4 w0 = *(const float4*)&wlds[w][r][0];
        const float4 w1 = *(const float4*)&wlds[w][r][4];
        float f0 = BFLO(fu[r].x), f1 = BFHI(fu[r].x), f2 = BFLO(fu[r].y), f3 = BFHI(fu[r].y);
        acc[0][0] += w0.x * f0; acc[0][1] += w0.x * f1; acc[0][2] += w0.x * f2; acc[0][3] += w0.x * f3;
        acc[1][0] += w0.y * f0; acc[1][1] += w0.y * f1; acc[1][2] += w0.y * f2; acc[1][3] += w0.y * f3;
        acc[2][0] += w0.z * f0; acc[2][1] += w0.z * f1; acc[2][2] += w0.z * f2; acc[2][3] += w0.z * f3;
        acc[3][0] += w0.w * f0; acc[3][1] += w0.w * f1; acc[3][2] += w0.w * f2; acc[3][3] += w0.w * f3;
        acc[4][0] += w1.x * f0; acc[4][1] += w1.x * f1; acc[4][2] += w1.x * f2; acc[4][3] += w1.x * f3;
        acc[5][0] += w1.y * f0; acc[5][1] += w1.y * f1; acc[5][2] += w1.y * f2; acc[5][3] += w1.y * f3;
        acc[6][0] += w1.z * f0; acc[6][1] += w1.z * f1; acc[6][2] += w1.z * f2; acc[6][3] += w1.z * f3;
        acc[7][0] += w1.w * f0; acc[7][1] += w1.w * f1; acc[7][2] += w1.w * f2; acc[7][3] += w1.w * f3;
      }
    } else {
      if (col == NHEAD) {
        float qm = qbkmean_s;
#pragma unroll
        for (int j = 0; j < 4; j++) a2buf[L + quad * 4 + j] = c[j] * 0.125f + qm;
      }
    }
  }

  // esum: combine quads (lanes h, h+16, h+32, h+48 all have col==h for h<8)
  esum_acc += __shfl_xor(esum_acc, 16, 64);
  esum_acc += __shfl_xor(esum_acc, 32, 64);
  if (lane < NHEAD) esums[w][lane] = esum_acc;
#pragma unroll
  for (int h = 0; h < NHEAD; h++) {
    atomicAdd(&fbar[h][lane * 4 + 0], acc[h][0]);
    atomicAdd(&fbar[h][lane * 4 + 1], acc[h][1]);
    atomicAdd(&fbar[h][lane * 4 + 2], acc[h][2]);
    atomicAdd(&fbar[h][lane * 4 + 3], acc[h][3]);
  }
  __syncthreads();

  {
    float v1 = a2buf[t];
    float v2 = (t < 128) ? a2buf[256 + t] : 0.f;
    float ls = v1 + v2, lq = v1 * v1 + v2 * v2;
#pragma unroll
    for (int off = 32; off >= 1; off >>= 1) { ls += __shfl_xor(ls, off, 64); lq += __shfl_xor(lq, off, 64); }
    if (lane == 0) { sstat[w][0] = ls; sstat[w][1] = lq; }
  }
  __syncthreads();
  if (t < NHEAD) {
    expsum_part[b * NHEAD + t] = esums[0][t] + esums[1][t] + esums[2][t] + esums[3][t];
  } else if (t == NHEAD) {
    stat_part[b * 2 + 0] = sstat[0][0] + sstat[1][0] + sstat[2][0] + sstat[3][0];
    stat_part[b * 2 + 1] = sstat[0][1] + sstat[1][1] + sstat[2][1] + sstat[3][1];
  }
  aff2_g[s * NSEL + half + 2 * t] = a2buf[t];
  if (t < 128) aff2_g[s * NSEL + half + 2 * (256 + t)] = a2buf[256 + t];
  ((float4*)(fbar_part + (size_t)b * 2048))[t] = ((float4*)fbar)[t];
  ((float4*)(fbar_part + (size_t)b * 2048))[t + 256] = ((float4*)fbar)[t + 256];
}

// ---------------- Kernel D: combine partials + Wv + out-proj + LN + norm_aff ----------------
__global__ __launch_bounds__(1024) void finish_kernel(
    const float* __restrict__ slots,
    const float* __restrict__ expsum_part, const float* __restrict__ stat_part,
    const float* __restrict__ aff2_g, const float* __restrict__ fbar_part,
    const float* __restrict__ ipw, const float* __restrict__ ipb,
    const float* __restrict__ wout, const float* __restrict__ bout,
    const float* __restrict__ lnw, const float* __restrict__ lnb,
    float* __restrict__ slots_new, float* __restrict__ norm_aff) {
  __shared__ float fbar[NHEAD][D_];
  __shared__ float srow[D_];
  __shared__ float outv[D_];
  __shared__ float pq[1024];
  __shared__ float redS[4], redQ[4];
  int s = blockIdx.x, t = threadIdx.x, wave = t >> 6, lane = t & 63;

  float st0 = stat_part[s * 4 + 0] + stat_part[s * 4 + 2];
  float st1 = stat_part[s * 4 + 1] + stat_part[s * 4 + 3];
  float mean_a = st0 * (1.0f / NSEL);
  float var_a = st1 * (1.0f / NSEL) - mean_a * mean_a;
  float rstd_a = rsqrtf(var_a + 1e-5f);
  if (t < NSEL) norm_aff[(size_t)t * NSLOT + s] = (aff2_g[s * NSEL + t] - mean_a) * rstd_a;

  if (t < 512) {
    int h = t >> 6;  // fbar layout [8][256]: 64 float4s per head
    float inv = 1.0f / (expsum_part[s * 16 + h] + expsum_part[s * 16 + 8 + h]);
    const float4 a = ((const float4*)(fbar_part + (size_t)s * 4096))[t];
    const float4 c = ((const float4*)(fbar_part + (size_t)s * 4096 + 2048))[t];
    float4 r;
    r.x = (a.x + c.x) * inv; r.y = (a.y + c.y) * inv;
    r.z = (a.z + c.z) * inv; r.w = (a.w + c.w) * inv;
    ((float4*)fbar)[t] = r;
  }
  if (t < 64) ((float4*)srow)[t] = ((const float4*)(slots + (size_t)s * D_))[t];
  __syncthreads();

  {
    int o = t >> 2, part = t & 3, h = o >> 5;
    const float4* wv = (const float4*)(ipw + (size_t)(2 * D_ + o) * D_ + part * 64);
    float a = 0.f;
#pragma unroll
    for (int i = 0; i < 16; i++) {
      float4 w = wv[i];
      int d = part * 64 + i * 4;
      a += fbar[h][d] * w.x + fbar[h][d + 1] * w.y + fbar[h][d + 2] * w.z + fbar[h][d + 3] * w.w;
    }
    pq[t] = a;
  }
  __syncthreads();
  if (t < D_)
    outv[t] = pq[t * 4] + pq[t * 4 + 1] + pq[t * 4 + 2] + pq[t * 4 + 3] + ipb[2 * D_ + t];
  __syncthreads();

  {
    int o = t >> 2, part = t & 3;
    const float4* w4 = (const float4*)(wout + (size_t)o * D_ + part * 64);
    float a = 0.f;
#pragma unroll
    for (int i = 0; i < 16; i++) {
      float4 w = w4[i];
      int d = part * 64 + i * 4;
      a += outv[d] * w.x + outv[d + 1] * w.y + outv[d + 2] * w.z + outv[d + 3] * w.w;
    }
    pq[t] = a;
  }
  __syncthreads();
  float v = 0.f;
  if (t < D_) {
    v = srow[t] + pq[t * 4] + pq[t * 4 + 1] + pq[t * 4 + 2] + pq[t * 4 + 3] + bout[t];
    float ls = v, lq = v * v;
#pragma unroll
    for (int off = 32; off >= 1; off >>= 1) { ls += __shfl_xor(ls, off, 64); lq += __shfl_xor(lq, off, 64); }
    if (lane == 0) { redS[wave] = ls; redQ[wave] = lq; }
  }
  __syncthreads();
  if (t < D_) {
    float tots = redS[0] + redS[1] + redS[2] + redS[3];
    float totq = redQ[0] + redQ[1] + redQ[2] + redQ[3];
    float mean = tots * (1.0f / D_);
    float var = totq * (1.0f / D_) - mean * mean;
    float rstd = rsqrtf(var + 1e-5f);
    slots_new[s * D_ + t] = (v - mean) * rstd * lnw[t] + lnb[t];
  }
}

extern "C" void kernel_launch(void* const* d_in, const int* in_sizes, int n_in,
                              void* d_out, int out_size, void* d_ws, size_t ws_size,
                              hipStream_t stream) {
  const float* slots    = (const float*)d_in[0];
  const float* features = (const float*)d_in[1];
  const float* posenc   = (const float*)d_in[2];
  const float* curio    = (const float*)d_in[3];
  const int*   batch_idx= (const int*)d_in[4];
  const float* ipw      = (const float*)d_in[5];
  const float* ipb      = (const float*)d_in[6];
  const float* wout     = (const float*)d_in[7];
  const float* bout     = (const float*)d_in[8];
  const float* lnw      = (const float*)d_in[9];
  const float* lnb      = (const float*)d_in[10];

  char* ws = (char*)d_ws;
  size_t off = 0;
  int*   feat_sel    = (int*)(ws + off);   off += 256 * 768 * 4;        // 786432
  float* qbk_g       = (float*)(ws + off); off += 256 * 8 * 4;          // 8192
  unsigned short* qkb16 = (unsigned short*)(ws + off); off += 256 * 4096 * 2; // 2097152
  float* fbar_part   = (float*)(ws + off); off += 256 * 2 * 8 * 256 * 4;// 4194304
  float* expsum_part = (float*)(ws + off); off += 256 * 2 * 8 * 4;      // 16384
  float* stat_part   = (float*)(ws + off); off += 256 * 2 * 2 * 4;      // 4096
  float* aff2_g      = (float*)(ws + off); off += 256 * 768 * 4;        // 786432
  size_t kpf_off = (off + 1023) & ~(size_t)1023;
  unsigned short* kpf = (unsigned short*)(ws + kpf_off);                // 67108864

  float* out_f = (float*)d_out;  // [0,65536) slots_new, [65536,262144) norm_aff

  prep_kernel<<<832, 1024, 0, stream>>>(curio, feat_sel, slots, ipw, ipb,
                                        qbk_g, qkb16, features, posenc, kpf);
  aff_pv_mfma_kernel<<<NSLOT * 2, 256, 0, stream>>>(kpf, qkb16, batch_idx, feat_sel,
                                                    qbk_g, fbar_part, expsum_part,
                                                    stat_part, aff2_g);
  finish_kernel<<<NSLOT, 1024, 0, stream>>>(slots, expsum_part, stat_part, aff2_g,
                                            fbar_part, ipw, ipb, wout, bout, lnw, lnb,
                                            out_f, out_f + 65536);
}

// Round 17
// 137.480 us; speedup vs baseline: 1.4133x; 1.0484x over previous
//
#include <hip/hip_runtime.h>
#include <math.h>

#define NSLOT 256
#define HWN   16384
#define D_    256
#define BB    4
#define NSEL  768
#define NPOS  512
#define NHEAD 8
#define SEGS  20                         // topk candidate capacity = 20*64 = 1280

typedef __attribute__((ext_vector_type(8))) short short8v;   // 8 bf16 (4 VGPRs)
typedef __attribute__((ext_vector_type(4))) float float4v;   // MFMA C/D

// global->LDS DMA: 16B per lane; LDS dest wave-uniform base; GLOBAL SOURCE PER-LANE.
#define GLD16(g, l)                                                        \
  __builtin_amdgcn_global_load_lds(                                        \
      (__attribute__((address_space(1))) void*)(g),                        \
      (__attribute__((address_space(3))) void*)(l), 16, 0, 0)

#define BFLO(u) __uint_as_float((u) << 16)
#define BFHI(u) __uint_as_float((u) & 0xffff0000u)

__device__ __forceinline__ unsigned short f2bf(float x) {   // RNE bf16
  unsigned u = __float_as_uint(x);
  unsigned r = u + 0x7fffu + ((u >> 16) & 1u);
  return (unsigned short)(r >> 16);
}
__device__ __forceinline__ unsigned int pk2(float a, float b) {
  return (unsigned)f2bf(a) | ((unsigned)f2bf(b) << 16);
}

// ---------------- Kernel PREP: fused topk (blocks 0-255) | qproj x4 slots (256-319)
//                  | pack (320-831, grid-strided). Independent inputs -> run concurrently.
// R16 lesson: topk's 55-barrier bitonic + serialized LDS atomics degraded ~3x under
// co-residency with pack. New topk: ballot-collect + wave-shuffle segment sort +
// merge-rank (binary search) -> ~6 barriers, no per-candidate atomics.
union PrepSmem {
  struct {
    unsigned int hist[4096];
    unsigned int wsum[16];
    unsigned long long skey[SEGS * 64];
    int sBstar;
    unsigned int sCount;
  } tk;                                   // ~26.7 KB
  struct {
    float srow[4][D_];
    float qrow[4][D_];
    float qkl[4][NHEAD][D_];
    float qsl[4][D_];
  } qp;                                   // 44 KB
};

__global__ __launch_bounds__(1024) void prep_kernel(
    const float* __restrict__ curio, int* __restrict__ feat_sel,
    const float* __restrict__ slots, const float* __restrict__ ipw,
    const float* __restrict__ ipb, float* __restrict__ qbk_g,
    unsigned short* __restrict__ qkb16,
    const float* __restrict__ fsrc, const float* __restrict__ psrc,
    unsigned short* __restrict__ kpf) {
  __shared__ PrepSmem sm;
  int B = blockIdx.x;
  int t = threadIdx.x;

  if (B < 256) {
    // ---------------- topk: per-slot top-768 stable select ----------------
    int s = B;
    int wave = t >> 6, lane = t & 63;
    const float* row = curio + (size_t)s * HWN;

    for (int i = t; i < 4096; i += 1024) sm.tk.hist[i] = 0;
    if (t == 0) sm.tk.sCount = 0;
    __syncthreads();
    for (int j = t; j < HWN; j += 1024) {
      unsigned int bits = __float_as_uint(row[j]);   // values in [0,1): bits monotone
      atomicAdd(&sm.tk.hist[bits >> 18], 1u);
    }
    __syncthreads();
    unsigned int cs = sm.tk.hist[t * 4] + sm.tk.hist[t * 4 + 1] +
                      sm.tk.hist[t * 4 + 2] + sm.tk.hist[t * 4 + 3];
    unsigned int v = cs;
#pragma unroll
    for (int off = 1; off < 64; off <<= 1) {
      unsigned int u = __shfl_down(v, off, 64);
      if (lane + off < 64) v += u;       // suffix over lanes >= lane (this wave)
    }
    if (lane == 0) sm.tk.wsum[wave] = v;
    __syncthreads();
    unsigned int above = 0;
    for (int w2 = wave + 1; w2 < 16; w2++) above += sm.tk.wsum[w2];
    unsigned int sufAfter = above + (v - cs);
    if (sufAfter < NSEL && sufAfter + cs >= NSEL) {
      unsigned int local = sufAfter;
      for (int b2 = t * 4 + 3; b2 >= t * 4; b2--) {
        unsigned int c = sm.tk.hist[b2];
        if (local + c >= NSEL) { sm.tk.sBstar = b2; break; }
        local += c;
      }
    }
    __syncthreads();
    int bstar = sm.tk.sBstar;
    // collect candidates: one atomic per wave-iteration (ballot aggregation)
    for (int j = t; j < HWN; j += 1024) {
      unsigned int bits = __float_as_uint(row[j]);
      bool cand = ((int)(bits >> 18) >= bstar);
      unsigned long long mask = __ballot(cand);
      unsigned int base = 0;
      int lcnt = __popcll(mask);
      if (lane == 0 && lcnt) base = atomicAdd(&sm.tk.sCount, (unsigned)lcnt);
      base = __shfl(base, 0, 64);
      if (cand) {
        unsigned pos = base + __popcll(mask & ((1ull << lane) - 1ull));
        if (pos < SEGS * 64)
          sm.tk.skey[pos] = ((unsigned long long)bits << 14) |
                            (unsigned long long)(16383 - j);
      }
    }
    __syncthreads();
    unsigned int M = sm.tk.sCount;
    if (M > SEGS * 64) M = SEGS * 64;
    for (int i = t; i < SEGS * 64; i += 1024) if (i >= (int)M) sm.tk.skey[i] = 0ull;
    __syncthreads();
    // wave-local bitonic sort (descending) of each 64-seg, pure shuffles
    for (int seg = wave; seg < SEGS; seg += 16) {
      unsigned long long kv = sm.tk.skey[seg * 64 + lane];
#pragma unroll
      for (int k = 2; k <= 64; k <<= 1) {
#pragma unroll
        for (int j2 = k >> 1; j2 > 0; j2 >>= 1) {
          unsigned long long o = __shfl_xor(kv, j2, 64);
          bool lower = ((lane & j2) == 0);
          bool descblk = ((lane & k) == 0);
          bool wantmax = (descblk == lower);
          kv = (wantmax == (kv >= o)) ? kv : o;
        }
      }
      sm.tk.skey[seg * 64 + lane] = kv;
    }
    __syncthreads();
    // merge-rank: rank = pos-in-own-seg + sum over other segs of count(> key)
    for (int e = t; e < SEGS * 64; e += 1024) {
      unsigned long long key = sm.tk.skey[e];
      if (key == 0ull) continue;  // padding
      int seg = e >> 6;
      int rank = e & 63;
      for (int g = 0; g < SEGS; g++) {
        if (g == seg) continue;
        const unsigned long long* sp = &sm.tk.skey[g * 64];
        int lo = 0, hi = 64;
        while (lo < hi) {
          int mid = (lo + hi) >> 1;
          if (sp[mid] > key) lo = mid + 1; else hi = mid;
        }
        rank += lo;
      }
      if (rank < NSEL) feat_sel[s * NSEL + rank] = 16383 - (int)(key & 16383ull);
    }
  } else if (B < 320) {
    // ---------------- qproj: 4 slots per block (sub = t>>8) ----------------
    int sub = t >> 8, tt = t & 255;
    int s = (B - 256) * 4 + sub;
    float* srow = sm.qp.srow[sub];
    float* qrow = sm.qp.qrow[sub];
    float* qsl = sm.qp.qsl[sub];
    srow[tt] = slots[s * D_ + tt];
    __syncthreads();
    {
      const float* wq = ipw + (size_t)tt * D_;
      float acc = ipb[tt];
      for (int d = 0; d < D_; d++) acc += srow[d] * wq[d];
      qrow[tt] = acc * 0.17677669529663689f;  // 1/sqrt(32)
    }
    __syncthreads();
    float qsum = 0.f;
    for (int h = 0; h < NHEAD; h++) {
      const float* wkbase = ipw + (size_t)(D_ + h * 32) * D_ + tt;
      float a = 0.f;
      for (int e = 0; e < 32; e++) a += qrow[h * 32 + e] * wkbase[(size_t)e * D_];
      sm.qp.qkl[sub][h][tt] = a;
      qsum += a;
    }
    qsl[tt] = qsum;
    if (tt < NHEAD) {
      float a = 0.f;
      for (int e = 0; e < 32; e++) a += qrow[tt * 32 + e] * ipb[D_ + tt * 32 + e];
      qbk_g[s * NHEAD + tt] = a;
    }
    __syncthreads();
    // qkb16[s][e], e = ((kc*64+l)*8+j): B-frag order. col=l&15; k=kc*32+((l>>4)&3)*8+j.
    for (int i = 0; i < 16; i++) {
      int e = tt * 16 + i;
      int kc = e >> 9, l = (e >> 3) & 63, j = e & 7;
      int cc = l & 15, k = kc * 32 + ((l >> 4) & 3) * 8 + j;
      float v = (cc < NHEAD) ? sm.qp.qkl[sub][cc][k] : ((cc == NHEAD) ? qsl[k] : 0.f);
      qkb16[(size_t)s * 4096 + e] = f2bf(v);
    }
  } else {
    // ---------------- pack: kpf rows (1KB): [0:512) sigma-swizzled bf16(f+p),
    //                  [512:1024) linear bf16(f) ----------------
    int stride = 512 * 1024;
    for (int u = (B - 320) * 1024 + t; u < HWN * BB * 32; u += stride) {
      int row = u >> 5, b2 = u & 31;
      int c8 = b2 << 3;
      const float4* f4 = (const float4*)(fsrc + (size_t)row * D_ + c8);
      const float4* p4 = (const float4*)(psrc + (size_t)row * D_ + c8);
      float4 a0 = f4[0], a1 = f4[1], b0 = p4[0], b1 = p4[1];
      uint4 kp, ff;
      kp.x = pk2(a0.x + b0.x, a0.y + b0.y);
      kp.y = pk2(a0.z + b0.z, a0.w + b0.w);
      kp.z = pk2(a1.x + b1.x, a1.y + b1.y);
      kp.w = pk2(a1.z + b1.z, a1.w + b1.w);
      ff.x = pk2(a0.x, a0.y); ff.y = pk2(a0.z, a0.w);
      ff.z = pk2(a1.x, a1.y); ff.w = pk2(a1.z, a1.w);
      int sig = row & 7;
      *(uint4*)(kpf + (size_t)row * 512 + ((b2 ^ sig) << 3)) = kp;
      *(uint4*)(kpf + (size_t)row * 512 + 256 + c8) = ff;
    }
  }
}

// ---------------- Kernel C (MFMA): aff via matrix cores + scalar PV (R15/R16, passing) ----------------
__global__ __launch_bounds__(256, 3) void aff_pv_mfma_kernel(
    const unsigned short* __restrict__ kpf,
    const unsigned short* __restrict__ qkb16,
    const int* __restrict__ batch_idx, const int* __restrict__ feat_sel,
    const float* __restrict__ qbk_g,
    float* __restrict__ fbar_part,    // [256][2][8][256]
    float* __restrict__ expsum_part,  // [256][2][8]
    float* __restrict__ stat_part,    // [256][2][2]
    float* __restrict__ aff2_g) {     // [256][768]
  __shared__ unsigned short kplds[4][4096];     // 32 KB: per-wave 16 rows x 512B (sigma layout)
  __shared__ unsigned short qkb[4096];          // 8 KB
  __shared__ float wlds[4][16][17];             // 4.3 KB
  __shared__ float fbar[NHEAD][D_];             // 8 KB
  __shared__ float a2buf[384];
  __shared__ int   sfsel[384];
  __shared__ float esums[4][NHEAD];
  __shared__ float sstat[4][2];
  __shared__ float qbkmean_s;

  int b = blockIdx.x, s = b >> 1, half = b & 1;
  int t = threadIdx.x, w = t >> 6, lane = t & 63;
  int bi = batch_idx[s];
  int col = lane & 15, quad = lane >> 4;

  {
    const uint4* src = (const uint4*)(qkb16 + (size_t)s * 4096);
    ((uint4*)qkb)[t] = src[t];
    ((uint4*)qkb)[t + 256] = src[t + 256];
  }
  for (int i = t; i < 384; i += 256) sfsel[i] = feat_sel[s * NSEL + half + 2 * i];
  for (int i = t; i < NHEAD * D_; i += 256) ((float*)fbar)[i] = 0.f;
  if (t == 0) {
    float m = 0.f;
    for (int h = 0; h < NHEAD; h++) m += qbk_g[s * NHEAD + h];
    qbkmean_s = m * 0.125f;
  }
  __syncthreads();

  unsigned short* kslot = &kplds[w][0];
  float acc[NHEAD][4];
#pragma unroll
  for (int h = 0; h < NHEAD; h++)
#pragma unroll
    for (int c = 0; c < 4; c++) acc[h][c] = 0.f;
  float esum_acc = 0.f;  // valid on lanes with col<8 (head=col)

  // 8 paired GLD16: lanes 0-31 <- row 2p kp-half, lanes 32-63 <- row 2p+1 kp-half.
  auto ISSUE_KP = [&](int L) {
#pragma unroll
    for (int p = 0; p < 8; p++) {
      int r0 = sfsel[L + 2 * p], r1 = sfsel[L + 2 * p + 1];
      unsigned ridx = (unsigned)((lane < 32 ? r0 : r1) * BB + bi);
      const unsigned short* src = kpf + (size_t)ridx * 512 + (lane & 31) * 8;
      GLD16(src, kslot + p * 512);
    }
  };

  ISSUE_KP(w * 64);  // prologue: tile 0
#pragma unroll 1
  for (int i = 0; i < 6; i++) {
    int L = (i < 4) ? (w * 64 + i * 16) : (256 + w * 32 + (i - 4) * 16);
    asm volatile("s_waitcnt vmcnt(0)" ::: "memory");  // tile i's 8 DMAs landed
    bool pos = (i < 4);
    uint2 fu[16];
    if (pos) {
#pragma unroll
      for (int r = 0; r < 16; r++)
        fu[r] = *(const uint2*)(kpf + (size_t)((unsigned)sfsel[L + r] * BB + bi) * 512 +
                                256 + lane * 4);
    }
    // A-frags: row col, k-block (kc*4+quad) xor sigma(row)
    unsigned sig = ((unsigned)sfsel[L + col] * BB + bi) & 7u;
    short8v afr[8];
#pragma unroll
    for (int kc = 0; kc < 8; kc++) {
      unsigned blk = ((unsigned)(kc * 4 + quad)) ^ sig;
      afr[kc] = *(const short8v*)(kslot + col * 256 + blk * 8);
    }
    asm volatile("s_waitcnt lgkmcnt(0)" ::: "memory");  // A reads done before slot reuse
    __builtin_amdgcn_sched_barrier(0);
    if (i < 5) {
      int Ln = (i < 3) ? (w * 64 + (i + 1) * 16) : (256 + w * 32 + (i - 3) * 16);
      ISSUE_KP(Ln);
    }
    float4v c = {0.f, 0.f, 0.f, 0.f};
#pragma unroll
    for (int kc = 0; kc < 8; kc++) {
      short8v bfr = *(const short8v*)&qkb[(kc * 64 + lane) * 8];
      c = __builtin_amdgcn_mfma_f32_16x16x32_bf16(afr[kc], bfr, c, 0, 0, 0);
    }
    // C: row n = quad*4+j (local row L+n), col: 0-7 heads, 8 = qksum-dot
    if (pos) {
      if (col < NHEAD) {
        float e0 = __expf(c[0]), e1 = __expf(c[1]), e2 = __expf(c[2]), e3 = __expf(c[3]);
        esum_acc += e0 + e1 + e2 + e3;
        wlds[w][quad * 4 + 0][col] = e0;
        wlds[w][quad * 4 + 1][col] = e1;
        wlds[w][quad * 4 + 2][col] = e2;
        wlds[w][quad * 4 + 3][col] = e3;
      } else if (col == NHEAD) {
        float qm = qbkmean_s;
#pragma unroll
        for (int j = 0; j < 4; j++) a2buf[L + quad * 4 + j] = c[j] * 0.125f + qm;
      }
      asm volatile("s_waitcnt lgkmcnt(0)" ::: "memory");  // wlds writes visible in-wave
      __builtin_amdgcn_sched_barrier(0);
#pragma unroll
      for (int r = 0; r < 16; r++) {
        const float4 w0 = *(const float4*)&wlds[w][r][0];
        const float4 w1 = *(const float4*)&wlds[w][r][4];
        float f0 = BFLO(fu[r].x), f1 = BFHI(fu[r].x), f2 = BFLO(fu[r].y), f3 = BFHI(fu[r].y);
        acc[0][0] += w0.x * f0; acc[0][1] += w0.x * f1; acc[0][2] += w0.x * f2; acc[0][3] += w0.x * f3;
        acc[1][0] += w0.y * f0; acc[1][1] += w0.y * f1; acc[1][2] += w0.y * f2; acc[1][3] += w0.y * f3;
        acc[2][0] += w0.z * f0; acc[2][1] += w0.z * f1; acc[2][2] += w0.z * f2; acc[2][3] += w0.z * f3;
        acc[3][0] += w0.w * f0; acc[3][1] += w0.w * f1; acc[3][2] += w0.w * f2; acc[3][3] += w0.w * f3;
        acc[4][0] += w1.x * f0; acc[4][1] += w1.x * f1; acc[4][2] += w1.x * f2; acc[4][3] += w1.x * f3;
        acc[5][0] += w1.y * f0; acc[5][1] += w1.y * f1; acc[5][2] += w1.y * f2; acc[5][3] += w1.y * f3;
        acc[6][0] += w1.z * f0; acc[6][1] += w1.z * f1; acc[6][2] += w1.z * f2; acc[6][3] += w1.z * f3;
        acc[7][0] += w1.w * f0; acc[7][1] += w1.w * f1; acc[7][2] += w1.w * f2; acc[7][3] += w1.w * f3;
      }
    } else {
      if (col == NHEAD) {
        float qm = qbkmean_s;
#pragma unroll
        for (int j = 0; j < 4; j++) a2buf[L + quad * 4 + j] = c[j] * 0.125f + qm;
      }
    }
  }

  // esum: combine quads (lanes h, h+16, h+32, h+48 all have col==h for h<8)
  esum_acc += __shfl_xor(esum_acc, 16, 64);
  esum_acc += __shfl_xor(esum_acc, 32, 64);
  if (lane < NHEAD) esums[w][lane] = esum_acc;
#pragma unroll
  for (int h = 0; h < NHEAD; h++) {
    atomicAdd(&fbar[h][lane * 4 + 0], acc[h][0]);
    atomicAdd(&fbar[h][lane * 4 + 1], acc[h][1]);
    atomicAdd(&fbar[h][lane * 4 + 2], acc[h][2]);
    atomicAdd(&fbar[h][lane * 4 + 3], acc[h][3]);
  }
  __syncthreads();

  {
    float v1 = a2buf[t];
    float v2 = (t < 128) ? a2buf[256 + t] : 0.f;
    float ls = v1 + v2, lq = v1 * v1 + v2 * v2;
#pragma unroll
    for (int off = 32; off >= 1; off >>= 1) { ls += __shfl_xor(ls, off, 64); lq += __shfl_xor(lq, off, 64); }
    if (lane == 0) { sstat[w][0] = ls; sstat[w][1] = lq; }
  }
  __syncthreads();
  if (t < NHEAD) {
    expsum_part[b * NHEAD + t] = esums[0][t] + esums[1][t] + esums[2][t] + esums[3][t];
  } else if (t == NHEAD) {
    stat_part[b * 2 + 0] = sstat[0][0] + sstat[1][0] + sstat[2][0] + sstat[3][0];
    stat_part[b * 2 + 1] = sstat[0][1] + sstat[1][1] + sstat[2][1] + sstat[3][1];
  }
  aff2_g[s * NSEL + half + 2 * t] = a2buf[t];
  if (t < 128) aff2_g[s * NSEL + half + 2 * (256 + t)] = a2buf[256 + t];
  ((float4*)(fbar_part + (size_t)b * 2048))[t] = ((float4*)fbar)[t];
  ((float4*)(fbar_part + (size_t)b * 2048))[t + 256] = ((float4*)fbar)[t + 256];
}

// ---------------- Kernel D: combine partials + Wv + out-proj + LN + norm_aff ----------------
__global__ __launch_bounds__(1024) void finish_kernel(
    const float* __restrict__ slots,
    const float* __restrict__ expsum_part, const float* __restrict__ stat_part,
    const float* __restrict__ aff2_g, const float* __restrict__ fbar_part,
    const float* __restrict__ ipw, const float* __restrict__ ipb,
    const float* __restrict__ wout, const float* __restrict__ bout,
    const float* __restrict__ lnw, const float* __restrict__ lnb,
    float* __restrict__ slots_new, float* __restrict__ norm_aff) {
  __shared__ float fbar[NHEAD][D_];
  __shared__ float srow[D_];
  __shared__ float outv[D_];
  __shared__ float pq[1024];
  __shared__ float redS[4], redQ[4];
  int s = blockIdx.x, t = threadIdx.x, wave = t >> 6, lane = t & 63;

  float st0 = stat_part[s * 4 + 0] + stat_part[s * 4 + 2];
  float st1 = stat_part[s * 4 + 1] + stat_part[s * 4 + 3];
  float mean_a = st0 * (1.0f / NSEL);
  float var_a = st1 * (1.0f / NSEL) - mean_a * mean_a;
  float rstd_a = rsqrtf(var_a + 1e-5f);
  if (t < NSEL) norm_aff[(size_t)t * NSLOT + s] = (aff2_g[s * NSEL + t] - mean_a) * rstd_a;

  if (t < 512) {
    int h = t >> 6;  // fbar layout [8][256]: 64 float4s per head
    float inv = 1.0f / (expsum_part[s * 16 + h] + expsum_part[s * 16 + 8 + h]);
    const float4 a = ((const float4*)(fbar_part + (size_t)s * 4096))[t];
    const float4 c = ((const float4*)(fbar_part + (size_t)s * 4096 + 2048))[t];
    float4 r;
    r.x = (a.x + c.x) * inv; r.y = (a.y + c.y) * inv;
    r.z = (a.z + c.z) * inv; r.w = (a.w + c.w) * inv;
    ((float4*)fbar)[t] = r;
  }
  if (t < 64) ((float4*)srow)[t] = ((const float4*)(slots + (size_t)s * D_))[t];
  __syncthreads();

  {
    int o = t >> 2, part = t & 3, h = o >> 5;
    const float4* wv = (const float4*)(ipw + (size_t)(2 * D_ + o) * D_ + part * 64);
    float a = 0.f;
#pragma unroll
    for (int i = 0; i < 16; i++) {
      float4 w = wv[i];
      int d = part * 64 + i * 4;
      a += fbar[h][d] * w.x + fbar[h][d + 1] * w.y + fbar[h][d + 2] * w.z + fbar[h][d + 3] * w.w;
    }
    pq[t] = a;
  }
  __syncthreads();
  if (t < D_)
    outv[t] = pq[t * 4] + pq[t * 4 + 1] + pq[t * 4 + 2] + pq[t * 4 + 3] + ipb[2 * D_ + t];
  __syncthreads();

  {
    int o = t >> 2, part = t & 3;
    const float4* w4 = (const float4*)(wout + (size_t)o * D_ + part * 64);
    float a = 0.f;
#pragma unroll
    for (int i = 0; i < 16; i++) {
      float4 w = w4[i];
      int d = part * 64 + i * 4;
      a += outv[d] * w.x + outv[d + 1] * w.y + outv[d + 2] * w.z + outv[d + 3] * w.w;
    }
    pq[t] = a;
  }
  __syncthreads();
  float v = 0.f;
  if (t < D_) {
    v = srow[t] + pq[t * 4] + pq[t * 4 + 1] + pq[t * 4 + 2] + pq[t * 4 + 3] + bout[t];
    float ls = v, lq = v * v;
#pragma unroll
    for (int off = 32; off >= 1; off >>= 1) { ls += __shfl_xor(ls, off, 64); lq += __shfl_xor(lq, off, 64); }
    if (lane == 0) { redS[wave] = ls; redQ[wave] = lq; }
  }
  __syncthreads();
  if (t < D_) {
    float tots = redS[0] + redS[1] + redS[2] + redS[3];
    float totq = redQ[0] + redQ[1] + redQ[2] + redQ[3];
    float mean = tots * (1.0f / D_);
    float var = totq * (1.0f / D_) - mean * mean;
    float rstd = rsqrtf(var + 1e-5f);
    slots_new[s * D_ + t] = (v - mean) * rstd * lnw[t] + lnb[t];
  }
}

extern "C" void kernel_launch(void* const* d_in, const int* in_sizes, int n_in,
                              void* d_out, int out_size, void* d_ws, size_t ws_size,
                              hipStream_t stream) {
  const float* slots    = (const float*)d_in[0];
  const float* features = (const float*)d_in[1];
  const float* posenc   = (const float*)d_in[2];
  const float* curio    = (const float*)d_in[3];
  const int*   batch_idx= (const int*)d_in[4];
  const float* ipw      = (const float*)d_in[5];
  const float* ipb      = (const float*)d_in[6];
  const float* wout     = (const float*)d_in[7];
  const float* bout     = (const float*)d_in[8];
  const float* lnw      = (const float*)d_in[9];
  const float* lnb      = (const float*)d_in[10];

  char* ws = (char*)d_ws;
  size_t off = 0;
  int*   feat_sel    = (int*)(ws + off);   off += 256 * 768 * 4;        // 786432
  float* qbk_g       = (float*)(ws + off); off += 256 * 8 * 4;          // 8192
  unsigned short* qkb16 = (unsigned short*)(ws + off); off += 256 * 4096 * 2; // 2097152
  float* fbar_part   = (float*)(ws + off); off += 256 * 2 * 8 * 256 * 4;// 4194304
  float* expsum_part = (float*)(ws + off); off += 256 * 2 * 8 * 4;      // 16384
  float* stat_part   = (float*)(ws + off); off += 256 * 2 * 2 * 4;      // 4096
  float* aff2_g      = (float*)(ws + off); off += 256 * 768 * 4;        // 786432
  size_t kpf_off = (off + 1023) & ~(size_t)1023;
  unsigned short* kpf = (unsigned short*)(ws + kpf_off);                // 67108864

  float* out_f = (float*)d_out;  // [0,65536) slots_new, [65536,262144) norm_aff

  prep_kernel<<<832, 1024, 0, stream>>>(curio, feat_sel, slots, ipw, ipb,
                                        qbk_g, qkb16, features, posenc, kpf);
  aff_pv_mfma_kernel<<<NSLOT * 2, 256, 0, stream>>>(kpf, qkb16, batch_idx, feat_sel,
                                                    qbk_g, fbar_part, expsum_part,
                                                    stat_part, aff2_g);
  finish_kernel<<<NSLOT, 1024, 0, stream>>>(slots, expsum_part, stat_part, aff2_g,
                                            fbar_part, ipw, ipb, wout, bout, lnw, lnb,
                                            out_f, out_f + 65536);
}